// Round 8
// baseline (174.709 us; speedup 1.0000x reference)
//
#include <hip/hip_runtime.h>
#include <hip/hip_bf16.h>

typedef __bf16 v4bf __attribute__((ext_vector_type(4)));
typedef __bf16 v8bf __attribute__((ext_vector_type(8)));
typedef float  v4f  __attribute__((ext_vector_type(4)));

namespace {
constexpr int Bb  = 2;
constexpr int Ss  = 2048;
constexpr int Dd  = 640;
constexpr int Hh  = 8;
constexpr int DHh = 80;
constexpr int Mm  = Bb * Ss;          // 4096 rows
// scale * log2(e): softmax done in exp2 domain; folded into Q projection
constexpr float kQScale = 0.11180339887498949f * 1.4426950408889634f;

__device__ __forceinline__ float4 ld4(const float* p) {
  return *reinterpret_cast<const float4*>(p);
}

__device__ __forceinline__ v8bf pack8(float4 f0, float4 f1) {
  v8bf p;
  p[0]=(__bf16)f0.x; p[1]=(__bf16)f0.y; p[2]=(__bf16)f0.z; p[3]=(__bf16)f0.w;
  p[4]=(__bf16)f1.x; p[5]=(__bf16)f1.y; p[6]=(__bf16)f1.z; p[7]=(__bf16)f1.w;
  return p;
}

// raw v_exp_f32 (2^x). exp2f without -ffast-math expands to libm range
// reduction (~10 VALU/call) — that was the attn VALUBusy=35% hotspot.
// Arg is bounded (|S*scale*log2e| < ~6) so the bare HW op is safe.
__device__ __forceinline__ float exp2_hw(float x) {
  float r;
  asm("v_exp_f32 %0, %1" : "=v"(r) : "v"(x));
  return r;
}
}  // namespace

// ---------------------------------------------------------------------------
// Pre-kernel: W [k][n] fp32 -> Wt [n][k] bf16 (cast + transpose).
// ---------------------------------------------------------------------------
__global__ __launch_bounds__(256)
void wtrans_kernel(const float* __restrict__ Wq, const float* __restrict__ Wk,
                   const float* __restrict__ Wv, const float* __restrict__ Wo,
                   __bf16* __restrict__ Wtq, __bf16* __restrict__ Wtk,
                   __bf16* __restrict__ Wtv, __bf16* __restrict__ Wto) {
  const int z = blockIdx.z;
  const float* W = (z == 0) ? Wq : (z == 1) ? Wk : (z == 2) ? Wv : Wo;
  __bf16* Wt = (z == 0) ? Wtq : (z == 1) ? Wtk : (z == 2) ? Wtv : Wto;
  const int k0 = blockIdx.y * 32, n0 = blockIdx.x * 32;
  __shared__ float t[32][33];
  const int tid = threadIdx.x;
  {
    int kr = tid >> 3, c4 = (tid & 7) * 4;
    float4 f = ld4(W + (size_t)(k0 + kr) * Dd + n0 + c4);
    t[kr][c4 + 0] = f.x; t[kr][c4 + 1] = f.y;
    t[kr][c4 + 2] = f.z; t[kr][c4 + 3] = f.w;
  }
  __syncthreads();
  {
    int nr = tid >> 3, kc = (tid & 7) * 4;
    v4bf p;
#pragma unroll
    for (int u = 0; u < 4; ++u) p[u] = (__bf16)t[kc + u][nr];
    *reinterpret_cast<v4bf*>(&Wt[(size_t)(n0 + nr) * Dd + k0 + kc]) = p;
  }
}

// ---------------------------------------------------------------------------
// Double-buffered MFMA GEMM core (reg-staged). C = A @ Bt^T. 128x128, BK=32.
// Used by the out-projection (bf16 A).
// ---------------------------------------------------------------------------
template <bool AF32>
__device__ __forceinline__ void gemm_core_db(const void* __restrict__ Ap,
                                             const __bf16* __restrict__ Bt,
                                             __bf16* As, __bf16* Bs, int m0,
                                             int n0, int rh, int ch,
                                             v4f acc[4][4]) {
  constexpr int BUF = 128 * 40;  // elements per buffer
  constexpr int NKB = Dd / 32;   // 20 K-steps
  const int tid = threadIdx.x;
  const int lane = tid & 63;
  const int quad = lane >> 4, l15 = lane & 15;
  const int lr = tid >> 1;
  const int lk = (tid & 1) * 16;
  const __bf16* Bg = Bt + (size_t)(n0 + lr) * Dd + lk;
  const float* Af = (const float*)Ap;
  const __bf16* Ab = (const __bf16*)Ap;

#pragma unroll
  for (int i = 0; i < 4; ++i)
#pragma unroll
    for (int j = 0; j < 4; ++j) acc[i][j] = (v4f){0.f, 0.f, 0.f, 0.f};

  v8bf a0, a1, b0, b1;
  if constexpr (AF32) {
    const float* ap = Af + (size_t)(m0 + lr) * Dd + lk;
    a0 = pack8(ld4(ap), ld4(ap + 4));
    a1 = pack8(ld4(ap + 8), ld4(ap + 12));
  } else {
    const __bf16* ap = Ab + (size_t)(m0 + lr) * Dd + lk;
    a0 = *reinterpret_cast<const v8bf*>(ap);
    a1 = *reinterpret_cast<const v8bf*>(ap + 8);
  }
  b0 = *reinterpret_cast<const v8bf*>(Bg);
  b1 = *reinterpret_cast<const v8bf*>(Bg + 8);
  *reinterpret_cast<v8bf*>(&As[lr * 40 + lk])     = a0;
  *reinterpret_cast<v8bf*>(&As[lr * 40 + lk + 8]) = a1;
  *reinterpret_cast<v8bf*>(&Bs[lr * 40 + lk])     = b0;
  *reinterpret_cast<v8bf*>(&Bs[lr * 40 + lk + 8]) = b1;

  for (int it = 0; it < NKB; ++it) {
    if (it + 1 < NKB) {
      const int kb = (it + 1) * 32;
      if constexpr (AF32) {
        const float* ap = Af + (size_t)(m0 + lr) * Dd + kb + lk;
        a0 = pack8(ld4(ap), ld4(ap + 4));
        a1 = pack8(ld4(ap + 8), ld4(ap + 12));
      } else {
        const __bf16* ap = Ab + (size_t)(m0 + lr) * Dd + kb + lk;
        a0 = *reinterpret_cast<const v8bf*>(ap);
        a1 = *reinterpret_cast<const v8bf*>(ap + 8);
      }
      b0 = *reinterpret_cast<const v8bf*>(Bg + kb);
      b1 = *reinterpret_cast<const v8bf*>(Bg + kb + 8);
    }
    __syncthreads();
    const int cur = (it & 1) * BUF, nxt = BUF - cur;
    v8bf af[4], bv[4];
#pragma unroll
    for (int i = 0; i < 4; ++i)
      af[i] = *reinterpret_cast<const v8bf*>(
          &As[cur + (rh + i * 16 + l15) * 40 + quad * 8]);
#pragma unroll
    for (int j = 0; j < 4; ++j)
      bv[j] = *reinterpret_cast<const v8bf*>(
          &Bs[cur + (ch + j * 16 + l15) * 40 + quad * 8]);
#pragma unroll
    for (int i = 0; i < 4; ++i)
#pragma unroll
      for (int j = 0; j < 4; ++j)
        acc[i][j] = __builtin_amdgcn_mfma_f32_16x16x32_bf16(af[i], bv[j],
                                                            acc[i][j], 0, 0, 0);
    if (it + 1 < NKB) {
      *reinterpret_cast<v8bf*>(&As[nxt + lr * 40 + lk])     = a0;
      *reinterpret_cast<v8bf*>(&As[nxt + lr * 40 + lk + 8]) = a1;
      *reinterpret_cast<v8bf*>(&Bs[nxt + lr * 40 + lk])     = b0;
      *reinterpret_cast<v8bf*>(&Bs[nxt + lr * 40 + lk + 8]) = b1;
    }
  }
}

// ---------------------------------------------------------------------------
// QKV projections (R8): z==0 -> Q = x@Wtq; z==1 -> K AND V fused from ehs
// (A-tile staged ONCE for both -> saves ~52MB of fp32 A re-fetch + half the
// ehs cvt VALU). z is the FASTEST grid dim so Q/KV blocks interleave across
// CUs (no serial tail of heavy KV blocks).
// Q,K head-packed [b][h][tok][80] (Q pre-scaled); V transposed [b][dim][tok].
// ---------------------------------------------------------------------------
__global__ __launch_bounds__(256, 1)
void gemm_qkv_mfma(const float* __restrict__ x, const float* __restrict__ ehs,
                   const __bf16* __restrict__ Wtq,
                   const __bf16* __restrict__ Wtk,
                   const __bf16* __restrict__ Wtv, __bf16* __restrict__ qb,
                   __bf16* __restrict__ kbuf, __bf16* __restrict__ vb) {
  constexpr int BUF = 128 * 40;
  constexpr int NKB = Dd / 32;
  const int z = blockIdx.x;  // 0: Q; 1: K+V fused
  __shared__ __bf16 As[2 * BUF];
  __shared__ __bf16 B0s[2 * BUF];
  __shared__ __bf16 B1s[2 * BUF];
  const int tid = threadIdx.x;
  const int w = tid >> 6, lane = tid & 63;
  const int quad = lane >> 4, l15 = lane & 15;
  const int m0 = blockIdx.z * 128, n0 = blockIdx.y * 128;
  const int rh = (w >> 1) * 64, ch = (w & 1) * 64;
  const int lr = tid >> 1, lk = (tid & 1) * 16;

  const float* A = z ? ehs : x;
  const __bf16* Bt0 = z ? Wtk : Wtq;
  const float* Ag = A + (size_t)(m0 + lr) * Dd + lk;
  const __bf16* B0g = Bt0 + (size_t)(n0 + lr) * Dd + lk;
  const __bf16* B1g = Wtv + (size_t)(n0 + lr) * Dd + lk;

  v4f acc0[4][4], acc1[4][4];
#pragma unroll
  for (int i = 0; i < 4; ++i)
#pragma unroll
    for (int j = 0; j < 4; ++j) {
      acc0[i][j] = (v4f){0.f, 0.f, 0.f, 0.f};
      acc1[i][j] = (v4f){0.f, 0.f, 0.f, 0.f};
    }

  v8bf a0, a1, b00, b01, b10, b11;
  a0 = pack8(ld4(Ag), ld4(Ag + 4));
  a1 = pack8(ld4(Ag + 8), ld4(Ag + 12));
  b00 = *reinterpret_cast<const v8bf*>(B0g);
  b01 = *reinterpret_cast<const v8bf*>(B0g + 8);
  if (z) {
    b10 = *reinterpret_cast<const v8bf*>(B1g);
    b11 = *reinterpret_cast<const v8bf*>(B1g + 8);
  }
  *reinterpret_cast<v8bf*>(&As[lr * 40 + lk])      = a0;
  *reinterpret_cast<v8bf*>(&As[lr * 40 + lk + 8])  = a1;
  *reinterpret_cast<v8bf*>(&B0s[lr * 40 + lk])     = b00;
  *reinterpret_cast<v8bf*>(&B0s[lr * 40 + lk + 8]) = b01;
  if (z) {
    *reinterpret_cast<v8bf*>(&B1s[lr * 40 + lk])     = b10;
    *reinterpret_cast<v8bf*>(&B1s[lr * 40 + lk + 8]) = b11;
  }

  for (int it = 0; it < NKB; ++it) {
    if (it + 1 < NKB) {
      const int kb = (it + 1) * 32;
      a0 = pack8(ld4(Ag + kb), ld4(Ag + kb + 4));
      a1 = pack8(ld4(Ag + kb + 8), ld4(Ag + kb + 12));
      b00 = *reinterpret_cast<const v8bf*>(B0g + kb);
      b01 = *reinterpret_cast<const v8bf*>(B0g + kb + 8);
      if (z) {
        b10 = *reinterpret_cast<const v8bf*>(B1g + kb);
        b11 = *reinterpret_cast<const v8bf*>(B1g + kb + 8);
      }
    }
    __syncthreads();
    const int cur = (it & 1) * BUF, nxt = BUF - cur;
    v8bf af[4], bv[4];
#pragma unroll
    for (int i = 0; i < 4; ++i)
      af[i] = *reinterpret_cast<const v8bf*>(
          &As[cur + (rh + i * 16 + l15) * 40 + quad * 8]);
#pragma unroll
    for (int j = 0; j < 4; ++j)
      bv[j] = *reinterpret_cast<const v8bf*>(
          &B0s[cur + (ch + j * 16 + l15) * 40 + quad * 8]);
#pragma unroll
    for (int i = 0; i < 4; ++i)
#pragma unroll
      for (int j = 0; j < 4; ++j)
        acc0[i][j] = __builtin_amdgcn_mfma_f32_16x16x32_bf16(
            af[i], bv[j], acc0[i][j], 0, 0, 0);
    if (z) {
#pragma unroll
      for (int j = 0; j < 4; ++j)
        bv[j] = *reinterpret_cast<const v8bf*>(
            &B1s[cur + (ch + j * 16 + l15) * 40 + quad * 8]);
#pragma unroll
      for (int i = 0; i < 4; ++i)
#pragma unroll
        for (int j = 0; j < 4; ++j)
          acc1[i][j] = __builtin_amdgcn_mfma_f32_16x16x32_bf16(
              af[i], bv[j], acc1[i][j], 0, 0, 0);
    }
    if (it + 1 < NKB) {
      *reinterpret_cast<v8bf*>(&As[nxt + lr * 40 + lk])      = a0;
      *reinterpret_cast<v8bf*>(&As[nxt + lr * 40 + lk + 8])  = a1;
      *reinterpret_cast<v8bf*>(&B0s[nxt + lr * 40 + lk])     = b00;
      *reinterpret_cast<v8bf*>(&B0s[nxt + lr * 40 + lk + 8]) = b01;
      if (z) {
        *reinterpret_cast<v8bf*>(&B1s[nxt + lr * 40 + lk])     = b10;
        *reinterpret_cast<v8bf*>(&B1s[nxt + lr * 40 + lk + 8]) = b11;
      }
    }
  }

  // ---- epilogues ----
  if (z == 0) {
    // Q head-packed, pre-scaled
#pragma unroll
    for (int i = 0; i < 4; ++i)
#pragma unroll
      for (int j = 0; j < 4; ++j) {
        int m = m0 + rh + i * 16 + quad * 4;
        int n = n0 + ch + j * 16 + l15;
        int hh = n / DHh, d = n % DHh;
        int bb = m >> 11, tok = m & 2047;
        __bf16* base = &qb[(((size_t)bb * Hh + hh) * Ss + tok) * DHh + d];
#pragma unroll
        for (int r = 0; r < 4; ++r)
          base[(size_t)r * DHh] = (__bf16)(acc0[i][j][r] * kQScale);
      }
  } else {
    // K head-packed
#pragma unroll
    for (int i = 0; i < 4; ++i)
#pragma unroll
      for (int j = 0; j < 4; ++j) {
        int m = m0 + rh + i * 16 + quad * 4;
        int n = n0 + ch + j * 16 + l15;
        int hh = n / DHh, d = n % DHh;
        int bb = m >> 11, tok = m & 2047;
        __bf16* base = &kbuf[(((size_t)bb * Hh + hh) * Ss + tok) * DHh + d];
#pragma unroll
        for (int r = 0; r < 4; ++r)
          base[(size_t)r * DHh] = (__bf16)acc0[i][j][r];
      }
    // V transposed [b][dim][token]
#pragma unroll
    for (int i = 0; i < 4; ++i)
#pragma unroll
      for (int j = 0; j < 4; ++j) {
        int m = m0 + rh + i * 16 + quad * 4;  // token
        int n = n0 + ch + j * 16 + l15;       // feature dim
        int bb = m >> 11, tok = m & 2047;
        v4bf pk;
#pragma unroll
        for (int r = 0; r < 4; ++r) pk[r] = (__bf16)acc1[i][j][r];
        *reinterpret_cast<v4bf*>(&vb[((size_t)bb * Dd + n) * Ss + tok]) = pk;
      }
  }
}

// Out-projection: A = attn-out bf16 [tok][640], out = fp32 + bias.
__global__ __launch_bounds__(256)
void gemm_out_mfma(const __bf16* __restrict__ A, const __bf16* __restrict__ Bt,
                   const float* __restrict__ bias, float* __restrict__ out) {
  __shared__ __bf16 As[2 * 128 * 40];
  __shared__ __bf16 Bs[2 * 128 * 40];
  const int tid = threadIdx.x;
  const int w = tid >> 6, lane = tid & 63;
  const int quad = lane >> 4, l15 = lane & 15;
  const int m0 = blockIdx.y * 128, n0 = blockIdx.x * 128;
  const int rh = (w >> 1) * 64, ch = (w & 1) * 64;
  v4f acc[4][4];
  gemm_core_db<false>(A, Bt, As, Bs, m0, n0, rh, ch, acc);

#pragma unroll
  for (int i = 0; i < 4; ++i)
#pragma unroll
    for (int j = 0; j < 4; ++j) {
      int m = m0 + rh + i * 16 + quad * 4;
      int n = n0 + ch + j * 16 + l15;
      float bn = bias[n];
#pragma unroll
      for (int r = 0; r < 4; ++r)
        out[(size_t)(m + r) * Dd + n] = acc[i][j][r] + bn;
    }
}

// ---------------------------------------------------------------------------
// Barrier-free key-split MFMA flash attention (R7 structure; R8 change:
// exp2f -> raw v_exp_f32, removing the libm range-reduction that made
// softmax the VALUBusy=35% hotspot). Everything else unchanged.
// ---------------------------------------------------------------------------
__global__ __launch_bounds__(256, 2)
void attn_mfma_kernel(const __bf16* __restrict__ q,
                      const __bf16* __restrict__ k,
                      const __bf16* __restrict__ vtg, __bf16* __restrict__ o) {
  constexpr int QT = 64;            // q rows per block (all waves)
  constexpr int KT = 32;            // keys per iteration per wave
  constexpr int KW = Ss / 4;        // 512 keys per wave
  constexpr int NIT = KW / KT;      // 16 iterations
  constexpr int LQ = 104;           // K row stride (96 dims + 8 pad)
  constexpr int LV = 40;            // V^T/P row stride (32 keys + 8 pad)
  constexpr int KS = KT * LQ;       // 3328
  constexpr int VS = 96 * LV;       // 3840 (80 data + ones + zeros)
  constexpr int PS = QT * LV;       // 2560
  constexpr int WSZ = KS + VS + PS; // 9728 bf16 per wave
  constexpr int LM = 100;           // merge row stride (f32)

  __shared__ __align__(16) __bf16 smem[4 * WSZ];  // 77824 B

  const int bh = blockIdx.x;        // XCD = linear%8 = bh%8 -> L2 locality
  const int b = bh >> 3, h = bh & 7;
  const int q0 = blockIdx.y * QT;
  const int tid = threadIdx.x;
  const int w = tid >> 6;
  const int lane = tid & 63;
  const int quad = lane >> 4;
  const int l15 = lane & 15;

  __bf16* ksw = smem + w * WSZ;
  __bf16* vtw = ksw + KS;
  __bf16* psw = vtw + VS;

  const __bf16* qg  = q + ((size_t)(b * Hh + h) * Ss + q0) * DHh;
  const __bf16* kgb = k + (size_t)(b * Hh + h) * Ss * DHh;
  const __bf16* vgb = vtg + ((size_t)b * Dd + h * DHh) * Ss;  // [dim][token]

  // ---- Q fragments straight from global (B-frag: n=q=l15, k=dim) ----
  v8bf qf[4][3];
#pragma unroll
  for (int qt = 0; qt < 4; ++qt)
#pragma unroll
    for (int s = 0; s < 3; ++s) {
      if (s == 2 && quad >= 2) {
        qf[qt][s] = (v8bf){};  // dims 80..95 = pad
      } else {
        qf[qt][s] = *reinterpret_cast<const v8bf*>(
            qg + (size_t)(qt * 16 + l15) * DHh + s * 32 + quad * 8);
      }
    }

  // per-lane staging geometry
  // K: tile is contiguous [32][80]; lane handles elems c*512 + lane*8
  int klr[5];
#pragma unroll
  for (int c = 0; c < 5; ++c) {
    int E = c * 512 + lane * 8;
    klr[c] = (E / DHh) * LQ + (E % DHh);   // LDS offset (16B-aligned)
  }
  const int vgo = (lane >> 2) * Ss + (lane & 3) * 8;   // global V (b128/lane)
  const int vlo = (lane >> 2) * LV + (lane & 3) * 8;   // LDS V (b128/lane)

  // ---- prologue: pads (written once; loop never touches them) ----
  {
    v8bf z8 = {};
    *reinterpret_cast<v8bf*>(&ksw[(lane >> 1) * LQ + 80 + (lane & 1) * 8]) = z8;
    v8bf pad = {};
    int vr = 80 + (lane >> 2);
    if (vr == 80) {
#pragma unroll
      for (int e = 0; e < 8; ++e) pad[e] = (__bf16)1.f;
    }
    *reinterpret_cast<v8bf*>(&vtw[vr * LV + (lane & 3) * 8]) = pad;
  }
  // ---- stage K(0): contiguous tile, 5 coalesced b128 per lane ----
  {
    const __bf16* kg = kgb + (size_t)(w * KW) * DHh;
#pragma unroll
    for (int c = 0; c < 5; ++c)
      *reinterpret_cast<v8bf*>(&ksw[klr[c]]) =
          *reinterpret_cast<const v8bf*>(kg + c * 512 + lane * 8);
  }

  v4f Oacc[4][6];
#pragma unroll
  for (int qt = 0; qt < 4; ++qt)
#pragma unroll
    for (int mt = 0; mt < 6; ++mt) Oacc[qt][mt] = (v4f){0.f, 0.f, 0.f, 0.f};

  // ---- main loop: per-wave, no barriers; 1-deep software pipeline ----
  for (int it = 0; it < NIT; ++it) {
    const bool pfK = (it + 1 < NIT);
    v8bf kreg[5];
    if (pfK) {
      const __bf16* kg = kgb + (size_t)(w * KW + (it + 1) * KT) * DHh;
#pragma unroll
      for (int c = 0; c < 5; ++c)
        kreg[c] = *reinterpret_cast<const v8bf*>(kg + c * 512 + lane * 8);
    }

    // ---- QK(it): S^T[key][q] ----
    v4f sacc[4][2];
#pragma unroll
    for (int qt = 0; qt < 4; ++qt) {
      sacc[qt][0] = (v4f){0.f, 0.f, 0.f, 0.f};
      sacc[qt][1] = (v4f){0.f, 0.f, 0.f, 0.f};
    }
    __builtin_amdgcn_s_setprio(1);
#pragma unroll
    for (int s = 0; s < 3; ++s) {
      v8bf ak0 = *reinterpret_cast<const v8bf*>(
          &ksw[l15 * LQ + s * 32 + quad * 8]);
      v8bf ak1 = *reinterpret_cast<const v8bf*>(
          &ksw[(16 + l15) * LQ + s * 32 + quad * 8]);
#pragma unroll
      for (int qt = 0; qt < 4; ++qt) {
        sacc[qt][0] = __builtin_amdgcn_mfma_f32_16x16x32_bf16(
            ak0, qf[qt][s], sacc[qt][0], 0, 0, 0);
        sacc[qt][1] = __builtin_amdgcn_mfma_f32_16x16x32_bf16(
            ak1, qf[qt][s], sacc[qt][1], 0, 0, 0);
      }
    }

    // V(it) loads (consumed by PV(it) next iter)
    v8bf vreg[5];
    {
      const __bf16* vg = vgb + (w * KW + it * KT);
#pragma unroll
      for (int c = 0; c < 5; ++c)
        vreg[c] = *reinterpret_cast<const v8bf*>(vg + vgo +
                                                 (size_t)c * 16 * Ss);
    }

    // ---- PV(it-1); exp2(it) fills its shadow ----
    if (it > 0) {
      v8bf bp[4];
#pragma unroll
      for (int qt = 0; qt < 4; ++qt)
        bp[qt] = *reinterpret_cast<const v8bf*>(
            &psw[(qt * 16 + l15) * LV + quad * 8]);
#pragma unroll
      for (int mt = 0; mt < 6; ++mt) {
        v8bf av = *reinterpret_cast<const v8bf*>(
            &vtw[(mt * 16 + l15) * LV + quad * 8]);
#pragma unroll
        for (int qt = 0; qt < 4; ++qt)
          Oacc[qt][mt] = __builtin_amdgcn_mfma_f32_16x16x32_bf16(
              av, bp[qt], Oacc[qt][mt], 0, 0, 0);
      }
    }
    __builtin_amdgcn_s_setprio(0);

    // ---- softmax(it): P = exp2(S) -> ps (raw v_exp_f32) ----
#pragma unroll
    for (int qt = 0; qt < 4; ++qt)
#pragma unroll
      for (int mt = 0; mt < 2; ++mt) {
        v4bf pk;
#pragma unroll
        for (int r = 0; r < 4; ++r)
          pk[r] = (__bf16)exp2_hw(sacc[qt][mt][r]);
        *reinterpret_cast<v4bf*>(
            &psw[(qt * 16 + l15) * LV + mt * 16 + quad * 4]) = pk;
      }

    // ---- commits ----
    if (pfK) {
#pragma unroll
      for (int c = 0; c < 5; ++c)
        *reinterpret_cast<v8bf*>(&ksw[klr[c]]) = kreg[c];
    }
#pragma unroll
    for (int c = 0; c < 5; ++c)
      *reinterpret_cast<v8bf*>(&vtw[vlo + c * 16 * LV]) = vreg[c];
  }

  // ---- pipeline epilogue: PV(NIT-1) ----
  {
    v8bf bp[4];
#pragma unroll
    for (int qt = 0; qt < 4; ++qt)
      bp[qt] = *reinterpret_cast<const v8bf*>(
          &psw[(qt * 16 + l15) * LV + quad * 8]);
    __builtin_amdgcn_s_setprio(1);
#pragma unroll
    for (int mt = 0; mt < 6; ++mt) {
      v8bf av = *reinterpret_cast<const v8bf*>(
          &vtw[(mt * 16 + l15) * LV + quad * 8]);
#pragma unroll
      for (int qt = 0; qt < 4; ++qt)
        Oacc[qt][mt] = __builtin_amdgcn_mfma_f32_16x16x32_bf16(
            av, bp[qt], Oacc[qt][mt], 0, 0, 0);
    }
    __builtin_amdgcn_s_setprio(0);
  }

  // ---- tree-merge the 4 per-wave partials ----
  __syncthreads();
  float* mrg = (float*)smem;
  if (w >= 2) {
    float* base = mrg + (w - 2) * (QT * LM);
#pragma unroll
    for (int qt = 0; qt < 4; ++qt)
#pragma unroll
      for (int mt = 0; mt < 6; ++mt)
        *reinterpret_cast<v4f*>(
            &base[(qt * 16 + l15) * LM + mt * 16 + quad * 4]) = Oacc[qt][mt];
  }
  __syncthreads();
  if (w < 2) {
    const float* base = mrg + w * (QT * LM);
#pragma unroll
    for (int qt = 0; qt < 4; ++qt)
#pragma unroll
      for (int mt = 0; mt < 6; ++mt)
        Oacc[qt][mt] += *reinterpret_cast<const v4f*>(
            &base[(qt * 16 + l15) * LM + mt * 16 + quad * 4]);
  }
  __syncthreads();
  if (w == 1) {
#pragma unroll
    for (int qt = 0; qt < 4; ++qt)
#pragma unroll
      for (int mt = 0; mt < 6; ++mt)
        *reinterpret_cast<v4f*>(
            &mrg[(qt * 16 + l15) * LM + mt * 16 + quad * 4]) = Oacc[qt][mt];
  }
  __syncthreads();
  if (w == 0) {
#pragma unroll
    for (int qt = 0; qt < 4; ++qt)
#pragma unroll
      for (int mt = 0; mt < 6; ++mt)
        Oacc[qt][mt] += *reinterpret_cast<const v4f*>(
            &mrg[(qt * 16 + l15) * LM + mt * 16 + quad * 4]);
#pragma unroll
    for (int qt = 0; qt < 4; ++qt) {
      float lsum = __shfl(Oacc[qt][5][0], l15);
      float inv = 1.f / lsum;
      __bf16* og =
          o + (size_t)(b * Ss + q0 + qt * 16 + l15) * Dd + h * DHh;
#pragma unroll
      for (int mt = 0; mt < 5; ++mt) {
        v4bf pk;
#pragma unroll
        for (int r = 0; r < 4; ++r) pk[r] = (__bf16)(Oacc[qt][mt][r] * inv);
        *reinterpret_cast<v4bf*>(&og[mt * 16 + quad * 4]) = pk;
      }
    }
  }
}

extern "C" void kernel_launch(void* const* d_in, const int* in_sizes, int n_in,
                              void* d_out, int out_size, void* d_ws,
                              size_t ws_size, hipStream_t stream) {
  const float* x   = (const float*)d_in[0];
  const float* ehs = (const float*)d_in[1];
  const float* Wq  = (const float*)d_in[2];
  const float* Wk  = (const float*)d_in[3];
  const float* Wv  = (const float*)d_in[4];
  const float* Wo  = (const float*)d_in[5];
  const float* bo  = (const float*)d_in[6];
  float* out = (float*)d_out;

  __bf16* qb  = (__bf16*)d_ws;                 // Q head-packed [2][8][2048][80]
  __bf16* kb  = qb + (size_t)Mm * Dd;          // K head-packed [2][8][2048][80]
  __bf16* vb  = kb + (size_t)Mm * Dd;          // V^T: [2][640][2048]
  __bf16* ab  = vb + (size_t)Mm * Dd;          // attention output [tok][640]
  __bf16* Wtq = ab + (size_t)Mm * Dd;          // [640][640] transposed
  __bf16* Wtk = Wtq + (size_t)Dd * Dd;
  __bf16* Wtv = Wtk + (size_t)Dd * Dd;
  __bf16* Wto = Wtv + (size_t)Dd * Dd;

  wtrans_kernel<<<dim3(Dd / 32, Dd / 32, 4), 256, 0, stream>>>(
      Wq, Wk, Wv, Wo, Wtq, Wtk, Wtv, Wto);
  gemm_qkv_mfma<<<dim3(2, Dd / 128, Mm / 128), 256, 0, stream>>>(
      x, ehs, Wtq, Wtk, Wtv, qb, kb, vb);
  attn_mfma_kernel<<<dim3(Bb * Hh, Ss / 64), 256, 0, stream>>>(qb, kb, vb, ab);
  gemm_out_mfma<<<dim3(Dd / 128, Mm / 128), 256, 0, stream>>>(ab, Wto, bo,
                                                              out);
}

// Round 9
// 150.075 us; speedup vs baseline: 1.1641x; 1.1641x over previous
//
#include <hip/hip_runtime.h>
#include <hip/hip_bf16.h>

typedef __bf16 v4bf __attribute__((ext_vector_type(4)));
typedef __bf16 v8bf __attribute__((ext_vector_type(8)));
typedef float  v4f  __attribute__((ext_vector_type(4)));

namespace {
constexpr int Bb  = 2;
constexpr int Ss  = 2048;
constexpr int Dd  = 640;
constexpr int Hh  = 8;
constexpr int DHh = 80;
constexpr int Mm  = Bb * Ss;          // 4096 rows
// scale * log2(e): softmax done in exp2 domain; folded into Q projection
constexpr float kQScale = 0.11180339887498949f * 1.4426950408889634f;

__device__ __forceinline__ float4 ld4(const float* p) {
  return *reinterpret_cast<const float4*>(p);
}

__device__ __forceinline__ v8bf pack8(float4 f0, float4 f1) {
  v8bf p;
  p[0]=(__bf16)f0.x; p[1]=(__bf16)f0.y; p[2]=(__bf16)f0.z; p[3]=(__bf16)f0.w;
  p[4]=(__bf16)f1.x; p[5]=(__bf16)f1.y; p[6]=(__bf16)f1.z; p[7]=(__bf16)f1.w;
  return p;
}

// raw v_exp_f32 (2^x). exp2f without -ffast-math expands to libm range
// reduction (~10 VALU/call). Arg is bounded (|S*scale*log2e| < ~6) so the
// bare HW op is safe. (R9: kept — this is the round's isolated attn delta.)
__device__ __forceinline__ float exp2_hw(float x) {
  float r;
  asm("v_exp_f32 %0, %1" : "=v"(r) : "v"(x));
  return r;
}
}  // namespace

// ---------------------------------------------------------------------------
// Pre-kernel: W [k][n] fp32 -> Wt [n][k] bf16 (cast + transpose).
// ---------------------------------------------------------------------------
__global__ __launch_bounds__(256)
void wtrans_kernel(const float* __restrict__ Wq, const float* __restrict__ Wk,
                   const float* __restrict__ Wv, const float* __restrict__ Wo,
                   __bf16* __restrict__ Wtq, __bf16* __restrict__ Wtk,
                   __bf16* __restrict__ Wtv, __bf16* __restrict__ Wto) {
  const int z = blockIdx.z;
  const float* W = (z == 0) ? Wq : (z == 1) ? Wk : (z == 2) ? Wv : Wo;
  __bf16* Wt = (z == 0) ? Wtq : (z == 1) ? Wtk : (z == 2) ? Wtv : Wto;
  const int k0 = blockIdx.y * 32, n0 = blockIdx.x * 32;
  __shared__ float t[32][33];
  const int tid = threadIdx.x;
  {
    int kr = tid >> 3, c4 = (tid & 7) * 4;
    float4 f = ld4(W + (size_t)(k0 + kr) * Dd + n0 + c4);
    t[kr][c4 + 0] = f.x; t[kr][c4 + 1] = f.y;
    t[kr][c4 + 2] = f.z; t[kr][c4 + 3] = f.w;
  }
  __syncthreads();
  {
    int nr = tid >> 3, kc = (tid & 7) * 4;
    v4bf p;
#pragma unroll
    for (int u = 0; u < 4; ++u) p[u] = (__bf16)t[kc + u][nr];
    *reinterpret_cast<v4bf*>(&Wt[(size_t)(n0 + nr) * Dd + k0 + kc]) = p;
  }
}

// ---------------------------------------------------------------------------
// Double-buffered MFMA GEMM core (reg-staged; R7 structure — the R8 fused
// variant regressed 19us: 320 blocks -> 1.25 blocks/CU, latency-bound at
// MfmaUtil 5%. Reverted). C = A @ Bt^T. 128x128 tile, BK=32, 4 waves.
// ---------------------------------------------------------------------------
template <bool AF32>
__device__ __forceinline__ void gemm_core_db(const void* __restrict__ Ap,
                                             const __bf16* __restrict__ Bt,
                                             __bf16* As, __bf16* Bs, int m0,
                                             int n0, int rh, int ch,
                                             v4f acc[4][4]) {
  constexpr int BUF = 128 * 40;  // elements per buffer
  constexpr int NKB = Dd / 32;   // 20 K-steps
  const int tid = threadIdx.x;
  const int lane = tid & 63;
  const int quad = lane >> 4, l15 = lane & 15;
  const int lr = tid >> 1;
  const int lk = (tid & 1) * 16;
  const __bf16* Bg = Bt + (size_t)(n0 + lr) * Dd + lk;
  const float* Af = (const float*)Ap;
  const __bf16* Ab = (const __bf16*)Ap;

#pragma unroll
  for (int i = 0; i < 4; ++i)
#pragma unroll
    for (int j = 0; j < 4; ++j) acc[i][j] = (v4f){0.f, 0.f, 0.f, 0.f};

  v8bf a0, a1, b0, b1;
  if constexpr (AF32) {
    const float* ap = Af + (size_t)(m0 + lr) * Dd + lk;
    a0 = pack8(ld4(ap), ld4(ap + 4));
    a1 = pack8(ld4(ap + 8), ld4(ap + 12));
  } else {
    const __bf16* ap = Ab + (size_t)(m0 + lr) * Dd + lk;
    a0 = *reinterpret_cast<const v8bf*>(ap);
    a1 = *reinterpret_cast<const v8bf*>(ap + 8);
  }
  b0 = *reinterpret_cast<const v8bf*>(Bg);
  b1 = *reinterpret_cast<const v8bf*>(Bg + 8);
  *reinterpret_cast<v8bf*>(&As[lr * 40 + lk])     = a0;
  *reinterpret_cast<v8bf*>(&As[lr * 40 + lk + 8]) = a1;
  *reinterpret_cast<v8bf*>(&Bs[lr * 40 + lk])     = b0;
  *reinterpret_cast<v8bf*>(&Bs[lr * 40 + lk + 8]) = b1;

  for (int it = 0; it < NKB; ++it) {
    if (it + 1 < NKB) {
      const int kb = (it + 1) * 32;
      if constexpr (AF32) {
        const float* ap = Af + (size_t)(m0 + lr) * Dd + kb + lk;
        a0 = pack8(ld4(ap), ld4(ap + 4));
        a1 = pack8(ld4(ap + 8), ld4(ap + 12));
      } else {
        const __bf16* ap = Ab + (size_t)(m0 + lr) * Dd + kb + lk;
        a0 = *reinterpret_cast<const v8bf*>(ap);
        a1 = *reinterpret_cast<const v8bf*>(ap + 8);
      }
      b0 = *reinterpret_cast<const v8bf*>(Bg + kb);
      b1 = *reinterpret_cast<const v8bf*>(Bg + kb + 8);
    }
    __syncthreads();
    const int cur = (it & 1) * BUF, nxt = BUF - cur;
    v8bf af[4], bv[4];
#pragma unroll
    for (int i = 0; i < 4; ++i)
      af[i] = *reinterpret_cast<const v8bf*>(
          &As[cur + (rh + i * 16 + l15) * 40 + quad * 8]);
#pragma unroll
    for (int j = 0; j < 4; ++j)
      bv[j] = *reinterpret_cast<const v8bf*>(
          &Bs[cur + (ch + j * 16 + l15) * 40 + quad * 8]);
#pragma unroll
    for (int i = 0; i < 4; ++i)
#pragma unroll
      for (int j = 0; j < 4; ++j)
        acc[i][j] = __builtin_amdgcn_mfma_f32_16x16x32_bf16(af[i], bv[j],
                                                            acc[i][j], 0, 0, 0);
    if (it + 1 < NKB) {
      *reinterpret_cast<v8bf*>(&As[nxt + lr * 40 + lk])     = a0;
      *reinterpret_cast<v8bf*>(&As[nxt + lr * 40 + lk + 8]) = a1;
      *reinterpret_cast<v8bf*>(&Bs[nxt + lr * 40 + lk])     = b0;
      *reinterpret_cast<v8bf*>(&Bs[nxt + lr * 40 + lk + 8]) = b1;
    }
  }
}

// QKV projections (R7 structure). z==0/1 -> Q/K written HEAD-PACKED
// [b][h][tok][80] (Q pre-scaled); z==2 -> V stored TRANSPOSED [b][dim][tok].
__global__ __launch_bounds__(256)
void gemm_qkv_mfma(const float* __restrict__ x, const float* __restrict__ ehs,
                   const __bf16* __restrict__ Wtq,
                   const __bf16* __restrict__ Wtk,
                   const __bf16* __restrict__ Wtv, __bf16* __restrict__ qb,
                   __bf16* __restrict__ kbuf, __bf16* __restrict__ vb) {
  const int z = blockIdx.z;
  const float* A = (z == 0) ? x : ehs;
  const __bf16* Bt = (z == 0) ? Wtq : (z == 1) ? Wtk : Wtv;
  __bf16* C = (z == 0) ? qb : (z == 1) ? kbuf : vb;
  const float scale = (z == 0) ? kQScale : 1.0f;

  __shared__ __bf16 As[2 * 128 * 40];
  __shared__ __bf16 Bs[2 * 128 * 40];
  const int tid = threadIdx.x;
  const int w = tid >> 6, lane = tid & 63;
  const int quad = lane >> 4, l15 = lane & 15;
  const int m0 = blockIdx.y * 128, n0 = blockIdx.x * 128;
  const int rh = (w >> 1) * 64, ch = (w & 1) * 64;
  v4f acc[4][4];
  gemm_core_db<true>(A, Bt, As, Bs, m0, n0, rh, ch, acc);

  if (z == 2) {
#pragma unroll
    for (int i = 0; i < 4; ++i)
#pragma unroll
      for (int j = 0; j < 4; ++j) {
        int m = m0 + rh + i * 16 + quad * 4;  // token row
        int n = n0 + ch + j * 16 + l15;       // feature dim
        int bb = m >> 11, tok = m & 2047;
        v4bf pk;
#pragma unroll
        for (int r = 0; r < 4; ++r) pk[r] = (__bf16)acc[i][j][r];
        *reinterpret_cast<v4bf*>(&C[((size_t)bb * Dd + n) * Ss + tok]) = pk;
      }
  } else {
    // head-packed epilogue: C[((b*Hh+h)*Ss + tok)*80 + d]
#pragma unroll
    for (int i = 0; i < 4; ++i)
#pragma unroll
      for (int j = 0; j < 4; ++j) {
        int m = m0 + rh + i * 16 + quad * 4;
        int n = n0 + ch + j * 16 + l15;
        int hh = n / DHh, d = n % DHh;
        int bb = m >> 11, tok = m & 2047;
        __bf16* base = &C[(((size_t)bb * Hh + hh) * Ss + tok) * DHh + d];
#pragma unroll
        for (int r = 0; r < 4; ++r)
          base[(size_t)r * DHh] = (__bf16)(acc[i][j][r] * scale);
      }
  }
}

// Out-projection: A = attn-out bf16 [tok][640], out = fp32 + bias.
__global__ __launch_bounds__(256)
void gemm_out_mfma(const __bf16* __restrict__ A, const __bf16* __restrict__ Bt,
                   const float* __restrict__ bias, float* __restrict__ out) {
  __shared__ __bf16 As[2 * 128 * 40];
  __shared__ __bf16 Bs[2 * 128 * 40];
  const int tid = threadIdx.x;
  const int w = tid >> 6, lane = tid & 63;
  const int quad = lane >> 4, l15 = lane & 15;
  const int m0 = blockIdx.y * 128, n0 = blockIdx.x * 128;
  const int rh = (w >> 1) * 64, ch = (w & 1) * 64;
  v4f acc[4][4];
  gemm_core_db<false>(A, Bt, As, Bs, m0, n0, rh, ch, acc);

#pragma unroll
  for (int i = 0; i < 4; ++i)
#pragma unroll
    for (int j = 0; j < 4; ++j) {
      int m = m0 + rh + i * 16 + quad * 4;
      int n = n0 + ch + j * 16 + l15;
      float bn = bias[n];
#pragma unroll
      for (int r = 0; r < 4; ++r)
        out[(size_t)(m + r) * Dd + n] = acc[i][j][r] + bn;
    }
}

// ---------------------------------------------------------------------------
// Barrier-free key-split MFMA flash attention (R7 structure; single R9 delta
// vs the measured-155.8 config: exp2f -> raw v_exp_f32).
// ---------------------------------------------------------------------------
__global__ __launch_bounds__(256, 2)
void attn_mfma_kernel(const __bf16* __restrict__ q,
                      const __bf16* __restrict__ k,
                      const __bf16* __restrict__ vtg, __bf16* __restrict__ o) {
  constexpr int QT = 64;            // q rows per block (all waves)
  constexpr int KT = 32;            // keys per iteration per wave
  constexpr int KW = Ss / 4;        // 512 keys per wave
  constexpr int NIT = KW / KT;      // 16 iterations
  constexpr int LQ = 104;           // K row stride (96 dims + 8 pad)
  constexpr int LV = 40;            // V^T/P row stride (32 keys + 8 pad)
  constexpr int KS = KT * LQ;       // 3328
  constexpr int VS = 96 * LV;       // 3840 (80 data + ones + zeros)
  constexpr int PS = QT * LV;       // 2560
  constexpr int WSZ = KS + VS + PS; // 9728 bf16 per wave
  constexpr int LM = 100;           // merge row stride (f32)

  __shared__ __align__(16) __bf16 smem[4 * WSZ];  // 77824 B

  const int bh = blockIdx.x;        // XCD = linear%8 = bh%8 -> L2 locality
  const int b = bh >> 3, h = bh & 7;
  const int q0 = blockIdx.y * QT;
  const int tid = threadIdx.x;
  const int w = tid >> 6;
  const int lane = tid & 63;
  const int quad = lane >> 4;
  const int l15 = lane & 15;

  __bf16* ksw = smem + w * WSZ;
  __bf16* vtw = ksw + KS;
  __bf16* psw = vtw + VS;

  const __bf16* qg  = q + ((size_t)(b * Hh + h) * Ss + q0) * DHh;
  const __bf16* kgb = k + (size_t)(b * Hh + h) * Ss * DHh;
  const __bf16* vgb = vtg + ((size_t)b * Dd + h * DHh) * Ss;  // [dim][token]

  // ---- Q fragments straight from global (B-frag: n=q=l15, k=dim) ----
  v8bf qf[4][3];
#pragma unroll
  for (int qt = 0; qt < 4; ++qt)
#pragma unroll
    for (int s = 0; s < 3; ++s) {
      if (s == 2 && quad >= 2) {
        qf[qt][s] = (v8bf){};  // dims 80..95 = pad
      } else {
        qf[qt][s] = *reinterpret_cast<const v8bf*>(
            qg + (size_t)(qt * 16 + l15) * DHh + s * 32 + quad * 8);
      }
    }

  // per-lane staging geometry
  // K: tile is contiguous [32][80]; lane handles elems c*512 + lane*8
  int klr[5];
#pragma unroll
  for (int c = 0; c < 5; ++c) {
    int E = c * 512 + lane * 8;
    klr[c] = (E / DHh) * LQ + (E % DHh);   // LDS offset (16B-aligned)
  }
  const int vgo = (lane >> 2) * Ss + (lane & 3) * 8;   // global V (b128/lane)
  const int vlo = (lane >> 2) * LV + (lane & 3) * 8;   // LDS V (b128/lane)

  // ---- prologue: pads (written once; loop never touches them) ----
  {
    v8bf z8 = {};
    *reinterpret_cast<v8bf*>(&ksw[(lane >> 1) * LQ + 80 + (lane & 1) * 8]) = z8;
    v8bf pad = {};
    int vr = 80 + (lane >> 2);
    if (vr == 80) {
#pragma unroll
      for (int e = 0; e < 8; ++e) pad[e] = (__bf16)1.f;
    }
    *reinterpret_cast<v8bf*>(&vtw[vr * LV + (lane & 3) * 8]) = pad;
  }
  // ---- stage K(0): contiguous tile, 5 coalesced b128 per lane ----
  {
    const __bf16* kg = kgb + (size_t)(w * KW) * DHh;
#pragma unroll
    for (int c = 0; c < 5; ++c)
      *reinterpret_cast<v8bf*>(&ksw[klr[c]]) =
          *reinterpret_cast<const v8bf*>(kg + c * 512 + lane * 8);
  }

  v4f Oacc[4][6];
#pragma unroll
  for (int qt = 0; qt < 4; ++qt)
#pragma unroll
    for (int mt = 0; mt < 6; ++mt) Oacc[qt][mt] = (v4f){0.f, 0.f, 0.f, 0.f};

  // ---- main loop: per-wave, no barriers; 1-deep software pipeline ----
  for (int it = 0; it < NIT; ++it) {
    const bool pfK = (it + 1 < NIT);
    v8bf kreg[5];
    if (pfK) {
      const __bf16* kg = kgb + (size_t)(w * KW + (it + 1) * KT) * DHh;
#pragma unroll
      for (int c = 0; c < 5; ++c)
        kreg[c] = *reinterpret_cast<const v8bf*>(kg + c * 512 + lane * 8);
    }

    // ---- QK(it): S^T[key][q] ----
    v4f sacc[4][2];
#pragma unroll
    for (int qt = 0; qt < 4; ++qt) {
      sacc[qt][0] = (v4f){0.f, 0.f, 0.f, 0.f};
      sacc[qt][1] = (v4f){0.f, 0.f, 0.f, 0.f};
    }
    __builtin_amdgcn_s_setprio(1);
#pragma unroll
    for (int s = 0; s < 3; ++s) {
      v8bf ak0 = *reinterpret_cast<const v8bf*>(
          &ksw[l15 * LQ + s * 32 + quad * 8]);
      v8bf ak1 = *reinterpret_cast<const v8bf*>(
          &ksw[(16 + l15) * LQ + s * 32 + quad * 8]);
#pragma unroll
      for (int qt = 0; qt < 4; ++qt) {
        sacc[qt][0] = __builtin_amdgcn_mfma_f32_16x16x32_bf16(
            ak0, qf[qt][s], sacc[qt][0], 0, 0, 0);
        sacc[qt][1] = __builtin_amdgcn_mfma_f32_16x16x32_bf16(
            ak1, qf[qt][s], sacc[qt][1], 0, 0, 0);
      }
    }

    // V(it) loads (consumed by PV(it) next iter)
    v8bf vreg[5];
    {
      const __bf16* vg = vgb + (w * KW + it * KT);
#pragma unroll
      for (int c = 0; c < 5; ++c)
        vreg[c] = *reinterpret_cast<const v8bf*>(vg + vgo +
                                                 (size_t)c * 16 * Ss);
    }

    // ---- PV(it-1); exp2(it) fills its shadow ----
    if (it > 0) {
      v8bf bp[4];
#pragma unroll
      for (int qt = 0; qt < 4; ++qt)
        bp[qt] = *reinterpret_cast<const v8bf*>(
            &psw[(qt * 16 + l15) * LV + quad * 8]);
#pragma unroll
      for (int mt = 0; mt < 6; ++mt) {
        v8bf av = *reinterpret_cast<const v8bf*>(
            &vtw[(mt * 16 + l15) * LV + quad * 8]);
#pragma unroll
        for (int qt = 0; qt < 4; ++qt)
          Oacc[qt][mt] = __builtin_amdgcn_mfma_f32_16x16x32_bf16(
              av, bp[qt], Oacc[qt][mt], 0, 0, 0);
      }
    }
    __builtin_amdgcn_s_setprio(0);

    // ---- softmax(it): P = exp2(S) -> ps (raw v_exp_f32) ----
#pragma unroll
    for (int qt = 0; qt < 4; ++qt)
#pragma unroll
      for (int mt = 0; mt < 2; ++mt) {
        v4bf pk;
#pragma unroll
        for (int r = 0; r < 4; ++r)
          pk[r] = (__bf16)exp2_hw(sacc[qt][mt][r]);
        *reinterpret_cast<v4bf*>(
            &psw[(qt * 16 + l15) * LV + mt * 16 + quad * 4]) = pk;
      }

    // ---- commits ----
    if (pfK) {
#pragma unroll
      for (int c = 0; c < 5; ++c)
        *reinterpret_cast<v8bf*>(&ksw[klr[c]]) = kreg[c];
    }
#pragma unroll
    for (int c = 0; c < 5; ++c)
      *reinterpret_cast<v8bf*>(&vtw[vlo + c * 16 * LV]) = vreg[c];
  }

  // ---- pipeline epilogue: PV(NIT-1) ----
  {
    v8bf bp[4];
#pragma unroll
    for (int qt = 0; qt < 4; ++qt)
      bp[qt] = *reinterpret_cast<const v8bf*>(
          &psw[(qt * 16 + l15) * LV + quad * 8]);
    __builtin_amdgcn_s_setprio(1);
#pragma unroll
    for (int mt = 0; mt < 6; ++mt) {
      v8bf av = *reinterpret_cast<const v8bf*>(
          &vtw[(mt * 16 + l15) * LV + quad * 8]);
#pragma unroll
      for (int qt = 0; qt < 4; ++qt)
        Oacc[qt][mt] = __builtin_amdgcn_mfma_f32_16x16x32_bf16(
            av, bp[qt], Oacc[qt][mt], 0, 0, 0);
    }
    __builtin_amdgcn_s_setprio(0);
  }

  // ---- tree-merge the 4 per-wave partials ----
  __syncthreads();
  float* mrg = (float*)smem;
  if (w >= 2) {
    float* base = mrg + (w - 2) * (QT * LM);
#pragma unroll
    for (int qt = 0; qt < 4; ++qt)
#pragma unroll
      for (int mt = 0; mt < 6; ++mt)
        *reinterpret_cast<v4f*>(
            &base[(qt * 16 + l15) * LM + mt * 16 + quad * 4]) = Oacc[qt][mt];
  }
  __syncthreads();
  if (w < 2) {
    const float* base = mrg + w * (QT * LM);
#pragma unroll
    for (int qt = 0; qt < 4; ++qt)
#pragma unroll
      for (int mt = 0; mt < 6; ++mt)
        Oacc[qt][mt] += *reinterpret_cast<const v4f*>(
            &base[(qt * 16 + l15) * LM + mt * 16 + quad * 4]);
  }
  __syncthreads();
  if (w == 1) {
#pragma unroll
    for (int qt = 0; qt < 4; ++qt)
#pragma unroll
      for (int mt = 0; mt < 6; ++mt)
        *reinterpret_cast<v4f*>(
            &mrg[(qt * 16 + l15) * LM + mt * 16 + quad * 4]) = Oacc[qt][mt];
  }
  __syncthreads();
  if (w == 0) {
#pragma unroll
    for (int qt = 0; qt < 4; ++qt)
#pragma unroll
      for (int mt = 0; mt < 6; ++mt)
        Oacc[qt][mt] += *reinterpret_cast<const v4f*>(
            &mrg[(qt * 16 + l15) * LM + mt * 16 + quad * 4]);
#pragma unroll
    for (int qt = 0; qt < 4; ++qt) {
      float lsum = __shfl(Oacc[qt][5][0], l15);
      float inv = 1.f / lsum;
      __bf16* og =
          o + (size_t)(b * Ss + q0 + qt * 16 + l15) * Dd + h * DHh;
#pragma unroll
      for (int mt = 0; mt < 5; ++mt) {
        v4bf pk;
#pragma unroll
        for (int r = 0; r < 4; ++r) pk[r] = (__bf16)(Oacc[qt][mt][r] * inv);
        *reinterpret_cast<v4bf*>(&og[mt * 16 + quad * 4]) = pk;
      }
    }
  }
}

extern "C" void kernel_launch(void* const* d_in, const int* in_sizes, int n_in,
                              void* d_out, int out_size, void* d_ws,
                              size_t ws_size, hipStream_t stream) {
  const float* x   = (const float*)d_in[0];
  const float* ehs = (const float*)d_in[1];
  const float* Wq  = (const float*)d_in[2];
  const float* Wk  = (const float*)d_in[3];
  const float* Wv  = (const float*)d_in[4];
  const float* Wo  = (const float*)d_in[5];
  const float* bo  = (const float*)d_in[6];
  float* out = (float*)d_out;

  __bf16* qb  = (__bf16*)d_ws;                 // Q head-packed [2][8][2048][80]
  __bf16* kb  = qb + (size_t)Mm * Dd;          // K head-packed [2][8][2048][80]
  __bf16* vb  = kb + (size_t)Mm * Dd;          // V^T: [2][640][2048]
  __bf16* ab  = vb + (size_t)Mm * Dd;          // attention output [tok][640]
  __bf16* Wtq = ab + (size_t)Mm * Dd;          // [640][640] transposed
  __bf16* Wtk = Wtq + (size_t)Dd * Dd;
  __bf16* Wtv = Wtk + (size_t)Dd * Dd;
  __bf16* Wto = Wtv + (size_t)Dd * Dd;

  wtrans_kernel<<<dim3(Dd / 32, Dd / 32, 4), 256, 0, stream>>>(
      Wq, Wk, Wv, Wo, Wtq, Wtk, Wtv, Wto);
  gemm_qkv_mfma<<<dim3(Dd / 128, Mm / 128, 3), 256, 0, stream>>>(
      x, ehs, Wtq, Wtk, Wtv, qb, kb, vb);
  attn_mfma_kernel<<<dim3(Bb * Hh, Ss / 64), 256, 0, stream>>>(qb, kb, vb, ab);
  gemm_out_mfma<<<dim3(Dd / 128, Mm / 128), 256, 0, stream>>>(ab, Wto, bo,
                                                              out);
}

// Round 11
// 147.803 us; speedup vs baseline: 1.1820x; 1.0154x over previous
//
#include <hip/hip_runtime.h>
#include <hip/hip_bf16.h>

typedef __bf16 v4bf __attribute__((ext_vector_type(4)));
typedef __bf16 v8bf __attribute__((ext_vector_type(8)));
typedef float  v4f  __attribute__((ext_vector_type(4)));

namespace {
constexpr int Bb  = 2;
constexpr int Ss  = 2048;
constexpr int Dd  = 640;
constexpr int Hh  = 8;
constexpr int DHh = 80;
constexpr int Mm  = Bb * Ss;          // 4096 rows
// scale * log2(e): softmax done in exp2 domain; folded into Q projection
constexpr float kQScale = 0.11180339887498949f * 1.4426950408889634f;

__device__ __forceinline__ float4 ld4(const float* p) {
  return *reinterpret_cast<const float4*>(p);
}

__device__ __forceinline__ v8bf pack8(float4 f0, float4 f1) {
  v8bf p;
  p[0]=(__bf16)f0.x; p[1]=(__bf16)f0.y; p[2]=(__bf16)f0.z; p[3]=(__bf16)f0.w;
  p[4]=(__bf16)f1.x; p[5]=(__bf16)f1.y; p[6]=(__bf16)f1.z; p[7]=(__bf16)f1.w;
  return p;
}

// raw v_exp_f32 (2^x): measured −5.7us vs libm exp2f (R9 A/B). Arg bounded.
__device__ __forceinline__ float exp2_hw(float x) {
  float r;
  asm("v_exp_f32 %0, %1" : "=v"(r) : "v"(x));
  return r;
}
}  // namespace

// ---------------------------------------------------------------------------
// Pre-kernel: W [k][n] fp32 -> Wt [n][k] bf16 (cast + transpose).
// ---------------------------------------------------------------------------
__global__ __launch_bounds__(256)
void wtrans_kernel(const float* __restrict__ Wq, const float* __restrict__ Wk,
                   const float* __restrict__ Wv, const float* __restrict__ Wo,
                   __bf16* __restrict__ Wtq, __bf16* __restrict__ Wtk,
                   __bf16* __restrict__ Wtv, __bf16* __restrict__ Wto) {
  const int z = blockIdx.z;
  const float* W = (z == 0) ? Wq : (z == 1) ? Wk : (z == 2) ? Wv : Wo;
  __bf16* Wt = (z == 0) ? Wtq : (z == 1) ? Wtk : (z == 2) ? Wtv : Wto;
  const int k0 = blockIdx.y * 32, n0 = blockIdx.x * 32;
  __shared__ float t[32][33];
  const int tid = threadIdx.x;
  {
    int kr = tid >> 3, c4 = (tid & 7) * 4;
    float4 f = ld4(W + (size_t)(k0 + kr) * Dd + n0 + c4);
    t[kr][c4 + 0] = f.x; t[kr][c4 + 1] = f.y;
    t[kr][c4 + 2] = f.z; t[kr][c4 + 3] = f.w;
  }
  __syncthreads();
  {
    int nr = tid >> 3, kc = (tid & 7) * 4;
    v4bf p;
#pragma unroll
    for (int u = 0; u < 4; ++u) p[u] = (__bf16)t[kc + u][nr];
    *reinterpret_cast<v4bf*>(&Wt[(size_t)(n0 + nr) * Dd + k0 + kc]) = p;
  }
}

// ---------------------------------------------------------------------------
// Double-buffered MFMA GEMM core (reg-staged, fp32 A). 128x128, BK=32.
// Used by the QKV projection.
// ---------------------------------------------------------------------------
__device__ __forceinline__ void gemm_core_db(const float* __restrict__ Af,
                                             const __bf16* __restrict__ Bt,
                                             __bf16* As, __bf16* Bs, int m0,
                                             int n0, int rh, int ch,
                                             v4f acc[4][4]) {
  constexpr int BUF = 128 * 40;  // elements per buffer
  constexpr int NKB = Dd / 32;   // 20 K-steps
  const int tid = threadIdx.x;
  const int lane = tid & 63;
  const int quad = lane >> 4, l15 = lane & 15;
  const int lr = tid >> 1;
  const int lk = (tid & 1) * 16;
  const __bf16* Bg = Bt + (size_t)(n0 + lr) * Dd + lk;

#pragma unroll
  for (int i = 0; i < 4; ++i)
#pragma unroll
    for (int j = 0; j < 4; ++j) acc[i][j] = (v4f){0.f, 0.f, 0.f, 0.f};

  v8bf a0, a1, b0, b1;
  {
    const float* ap = Af + (size_t)(m0 + lr) * Dd + lk;
    a0 = pack8(ld4(ap), ld4(ap + 4));
    a1 = pack8(ld4(ap + 8), ld4(ap + 12));
  }
  b0 = *reinterpret_cast<const v8bf*>(Bg);
  b1 = *reinterpret_cast<const v8bf*>(Bg + 8);
  *reinterpret_cast<v8bf*>(&As[lr * 40 + lk])     = a0;
  *reinterpret_cast<v8bf*>(&As[lr * 40 + lk + 8]) = a1;
  *reinterpret_cast<v8bf*>(&Bs[lr * 40 + lk])     = b0;
  *reinterpret_cast<v8bf*>(&Bs[lr * 40 + lk + 8]) = b1;

  for (int it = 0; it < NKB; ++it) {
    if (it + 1 < NKB) {
      const int kb = (it + 1) * 32;
      const float* ap = Af + (size_t)(m0 + lr) * Dd + kb + lk;
      a0 = pack8(ld4(ap), ld4(ap + 4));
      a1 = pack8(ld4(ap + 8), ld4(ap + 12));
      b0 = *reinterpret_cast<const v8bf*>(Bg + kb);
      b1 = *reinterpret_cast<const v8bf*>(Bg + kb + 8);
    }
    __syncthreads();
    const int cur = (it & 1) * BUF, nxt = BUF - cur;
    v8bf af[4], bv[4];
#pragma unroll
    for (int i = 0; i < 4; ++i)
      af[i] = *reinterpret_cast<const v8bf*>(
          &As[cur + (rh + i * 16 + l15) * 40 + quad * 8]);
#pragma unroll
    for (int j = 0; j < 4; ++j)
      bv[j] = *reinterpret_cast<const v8bf*>(
          &Bs[cur + (ch + j * 16 + l15) * 40 + quad * 8]);
#pragma unroll
    for (int i = 0; i < 4; ++i)
#pragma unroll
      for (int j = 0; j < 4; ++j)
        acc[i][j] = __builtin_amdgcn_mfma_f32_16x16x32_bf16(af[i], bv[j],
                                                            acc[i][j], 0, 0, 0);
    if (it + 1 < NKB) {
      *reinterpret_cast<v8bf*>(&As[nxt + lr * 40 + lk])     = a0;
      *reinterpret_cast<v8bf*>(&As[nxt + lr * 40 + lk + 8]) = a1;
      *reinterpret_cast<v8bf*>(&Bs[nxt + lr * 40 + lk])     = b0;
      *reinterpret_cast<v8bf*>(&Bs[nxt + lr * 40 + lk + 8]) = b1;
    }
  }
}

// QKV projections. z==0/1 -> Q/K HEAD-PACKED [b][h][tok][80] (Q pre-scaled);
// z==2 -> V^T TILED [b][h][tok/32][80][32] (R10: one contiguous 5KB block
// per attn iteration -> V staging fully coalesced, the K-fix analog).
__global__ __launch_bounds__(256)
void gemm_qkv_mfma(const float* __restrict__ x, const float* __restrict__ ehs,
                   const __bf16* __restrict__ Wtq,
                   const __bf16* __restrict__ Wtk,
                   const __bf16* __restrict__ Wtv, __bf16* __restrict__ qb,
                   __bf16* __restrict__ kbuf, __bf16* __restrict__ vb) {
  const int z = blockIdx.z;
  const float* A = (z == 0) ? x : ehs;
  const __bf16* Bt = (z == 0) ? Wtq : (z == 1) ? Wtk : Wtv;
  __bf16* C = (z == 0) ? qb : (z == 1) ? kbuf : vb;
  const float scale = (z == 0) ? kQScale : 1.0f;

  __shared__ __bf16 As[2 * 128 * 40];
  __shared__ __bf16 Bs[2 * 128 * 40];
  const int tid = threadIdx.x;
  const int w = tid >> 6, lane = tid & 63;
  const int quad = lane >> 4, l15 = lane & 15;
  const int m0 = blockIdx.y * 128, n0 = blockIdx.x * 128;
  const int rh = (w >> 1) * 64, ch = (w & 1) * 64;
  v4f acc[4][4];
  gemm_core_db(A, Bt, As, Bs, m0, n0, rh, ch, acc);

  if (z == 2) {
    // V^T tiled epilogue: vb[((b*Hh+h)*(Ss/32)+tb)*80 + d][t 0..31]
#pragma unroll
    for (int i = 0; i < 4; ++i)
#pragma unroll
      for (int j = 0; j < 4; ++j) {
        int m = m0 + rh + i * 16 + quad * 4;  // token (4 consecutive)
        int n = n0 + ch + j * 16 + l15;       // feature dim
        int hh = n / DHh, d = n % DHh;
        int bb = m >> 11, tok = m & 2047;
        int tb = tok >> 5, t = tok & 31;
        v4bf pk;
#pragma unroll
        for (int r = 0; r < 4; ++r) pk[r] = (__bf16)acc[i][j][r];
        *reinterpret_cast<v4bf*>(
            &C[((((size_t)bb * Hh + hh) * (Ss / 32) + tb) * DHh + d) * 32 +
               t]) = pk;
      }
  } else {
    // head-packed epilogue: C[((b*Hh+h)*Ss + tok)*80 + d]
#pragma unroll
    for (int i = 0; i < 4; ++i)
#pragma unroll
      for (int j = 0; j < 4; ++j) {
        int m = m0 + rh + i * 16 + quad * 4;
        int n = n0 + ch + j * 16 + l15;
        int hh = n / DHh, d = n % DHh;
        int bb = m >> 11, tok = m & 2047;
        __bf16* base = &C[(((size_t)bb * Hh + hh) * Ss + tok) * DHh + d];
#pragma unroll
        for (int r = 0; r < 4; ++r)
          base[(size_t)r * DHh] = (__bf16)(acc[i][j][r] * scale);
      }
  }
}

// ---------------------------------------------------------------------------
// Out-projection (R10): tile 128M x 64N -> grid 320 blocks (was 160 on 256
// CUs = 96 CUs idle, the round's main fix). 4 waves, each 64x32 (acc[4][2]).
// ---------------------------------------------------------------------------
__global__ __launch_bounds__(256)
void gemm_out_mfma(const __bf16* __restrict__ A, const __bf16* __restrict__ Bt,
                   const float* __restrict__ bias, float* __restrict__ out) {
  constexpr int BUFA = 128 * 40, BUFB = 64 * 40;
  constexpr int NKB = Dd / 32;
  __shared__ __bf16 As[2 * BUFA];
  __shared__ __bf16 Bs[2 * BUFB];
  const int tid = threadIdx.x;
  const int w = tid >> 6, lane = tid & 63;
  const int quad = lane >> 4, l15 = lane & 15;
  const int m0 = blockIdx.y * 128, n0 = blockIdx.x * 64;
  const int rh = (w >> 1) * 64, ch = (w & 1) * 32;
  const int lrA = tid >> 1, lkA = (tid & 1) * 16;
  const int lrB = tid >> 2, lkB = (tid & 3) * 8;
  const __bf16* Ag = A + (size_t)(m0 + lrA) * Dd + lkA;
  const __bf16* Bg = Bt + (size_t)(n0 + lrB) * Dd + lkB;

  v4f acc[4][2];
#pragma unroll
  for (int i = 0; i < 4; ++i)
#pragma unroll
    for (int j = 0; j < 2; ++j) acc[i][j] = (v4f){0.f, 0.f, 0.f, 0.f};

  v8bf a0, a1, b0;
  a0 = *reinterpret_cast<const v8bf*>(Ag);
  a1 = *reinterpret_cast<const v8bf*>(Ag + 8);
  b0 = *reinterpret_cast<const v8bf*>(Bg);
  *reinterpret_cast<v8bf*>(&As[lrA * 40 + lkA])     = a0;
  *reinterpret_cast<v8bf*>(&As[lrA * 40 + lkA + 8]) = a1;
  *reinterpret_cast<v8bf*>(&Bs[lrB * 40 + lkB])     = b0;

  for (int it = 0; it < NKB; ++it) {
    if (it + 1 < NKB) {
      const int kb = (it + 1) * 32;
      a0 = *reinterpret_cast<const v8bf*>(Ag + kb);
      a1 = *reinterpret_cast<const v8bf*>(Ag + kb + 8);
      b0 = *reinterpret_cast<const v8bf*>(Bg + kb);
    }
    __syncthreads();
    const int curA = (it & 1) * BUFA, nxtA = BUFA - curA;
    const int curB = (it & 1) * BUFB, nxtB = BUFB - curB;
    v8bf af[4], bv[2];
#pragma unroll
    for (int i = 0; i < 4; ++i)
      af[i] = *reinterpret_cast<const v8bf*>(
          &As[curA + (rh + i * 16 + l15) * 40 + quad * 8]);
#pragma unroll
    for (int j = 0; j < 2; ++j)
      bv[j] = *reinterpret_cast<const v8bf*>(
          &Bs[curB + (ch + j * 16 + l15) * 40 + quad * 8]);
#pragma unroll
    for (int i = 0; i < 4; ++i)
#pragma unroll
      for (int j = 0; j < 2; ++j)
        acc[i][j] = __builtin_amdgcn_mfma_f32_16x16x32_bf16(af[i], bv[j],
                                                            acc[i][j], 0, 0, 0);
    if (it + 1 < NKB) {
      *reinterpret_cast<v8bf*>(&As[nxtA + lrA * 40 + lkA])     = a0;
      *reinterpret_cast<v8bf*>(&As[nxtA + lrA * 40 + lkA + 8]) = a1;
      *reinterpret_cast<v8bf*>(&Bs[nxtB + lrB * 40 + lkB])     = b0;
    }
  }

#pragma unroll
  for (int i = 0; i < 4; ++i)
#pragma unroll
    for (int j = 0; j < 2; ++j) {
      int m = m0 + rh + i * 16 + quad * 4;
      int n = n0 + ch + j * 16 + l15;
      float bn = bias[n];
#pragma unroll
      for (int r = 0; r < 4; ++r)
        out[(size_t)(m + r) * Dd + n] = acc[i][j][r] + bn;
    }
}

// ---------------------------------------------------------------------------
// Barrier-free key-split MFMA flash attention (R9 structure; R10 delta:
// V^T global layout tiled [b][h][tok/32][80][32] -> V staging is 5 fully
// LINEAR b128 loads/lane (was a 16-line gather at 4KB stride). LDS layout
// and commit pattern unchanged.
// ---------------------------------------------------------------------------
__global__ __launch_bounds__(256, 2)
void attn_mfma_kernel(const __bf16* __restrict__ q,
                      const __bf16* __restrict__ k,
                      const __bf16* __restrict__ vtg, __bf16* __restrict__ o) {
  constexpr int QT = 64;            // q rows per block (all waves)
  constexpr int KT = 32;            // keys per iteration per wave
  constexpr int KW = Ss / 4;        // 512 keys per wave
  constexpr int NIT = KW / KT;      // 16 iterations
  constexpr int LQ = 104;           // K row stride (96 dims + 8 pad)
  constexpr int LV = 40;            // V^T/P row stride (32 keys + 8 pad)
  constexpr int KS = KT * LQ;       // 3328
  constexpr int VS = 96 * LV;       // 3840 (80 data + ones + zeros)
  constexpr int PS = QT * LV;       // 2560
  constexpr int WSZ = KS + VS + PS; // 9728 bf16 per wave
  constexpr int LM = 100;           // merge row stride (f32)

  __shared__ __align__(16) __bf16 smem[4 * WSZ];  // 77824 B

  const int bh = blockIdx.x;        // XCD = linear%8 = bh%8 -> L2 locality
  const int b = bh >> 3, h = bh & 7;
  const int q0 = blockIdx.y * QT;
  const int tid = threadIdx.x;
  const int w = tid >> 6;
  const int lane = tid & 63;
  const int quad = lane >> 4;
  const int l15 = lane & 15;

  __bf16* ksw = smem + w * WSZ;
  __bf16* vtw = ksw + KS;
  __bf16* psw = vtw + VS;

  const __bf16* qg  = q + ((size_t)(b * Hh + h) * Ss + q0) * DHh;
  const __bf16* kgb = k + (size_t)(b * Hh + h) * Ss * DHh;
  // tiled V^T: tile (w*16 + it) is one contiguous 80x32 block (5120B)
  const __bf16* vgb = vtg + (size_t)(b * Hh + h) * Ss * DHh;

  // ---- Q fragments straight from global (B-frag: n=q=l15, k=dim) ----
  v8bf qf[4][3];
#pragma unroll
  for (int qt = 0; qt < 4; ++qt)
#pragma unroll
    for (int s = 0; s < 3; ++s) {
      if (s == 2 && quad >= 2) {
        qf[qt][s] = (v8bf){};  // dims 80..95 = pad
      } else {
        qf[qt][s] = *reinterpret_cast<const v8bf*>(
            qg + (size_t)(qt * 16 + l15) * DHh + s * 32 + quad * 8);
      }
    }

  // per-lane staging geometry
  // K: tile contiguous [32][80]; lane handles elems c*512 + lane*8
  int klr[5];
#pragma unroll
  for (int c = 0; c < 5; ++c) {
    int E = c * 512 + lane * 8;
    klr[c] = (E / DHh) * LQ + (E % DHh);   // LDS offset (16B-aligned)
  }
  // V: tile contiguous [80 dims][32 tok]; elem e=c*512+lane*8 ->
  // dim d=c*16+(lane>>2), tok t=(lane&3)*8 -> LDS vlo + c*16*LV (unchanged)
  const int vlo = (lane >> 2) * LV + (lane & 3) * 8;

  // ---- prologue: pads (written once; loop never touches them) ----
  {
    v8bf z8 = {};
    *reinterpret_cast<v8bf*>(&ksw[(lane >> 1) * LQ + 80 + (lane & 1) * 8]) = z8;
    v8bf pad = {};
    int vr = 80 + (lane >> 2);
    if (vr == 80) {
#pragma unroll
      for (int e = 0; e < 8; ++e) pad[e] = (__bf16)1.f;
    }
    *reinterpret_cast<v8bf*>(&vtw[vr * LV + (lane & 3) * 8]) = pad;
  }
  // ---- stage K(0): contiguous tile, 5 coalesced b128 per lane ----
  {
    const __bf16* kg = kgb + (size_t)(w * KW) * DHh;
#pragma unroll
    for (int c = 0; c < 5; ++c)
      *reinterpret_cast<v8bf*>(&ksw[klr[c]]) =
          *reinterpret_cast<const v8bf*>(kg + c * 512 + lane * 8);
  }

  v4f Oacc[4][6];
#pragma unroll
  for (int qt = 0; qt < 4; ++qt)
#pragma unroll
    for (int mt = 0; mt < 6; ++mt) Oacc[qt][mt] = (v4f){0.f, 0.f, 0.f, 0.f};

  // ---- main loop: per-wave, no barriers; 1-deep software pipeline ----
  for (int it = 0; it < NIT; ++it) {
    const bool pfK = (it + 1 < NIT);
    v8bf kreg[5];
    if (pfK) {
      const __bf16* kg = kgb + (size_t)(w * KW + (it + 1) * KT) * DHh;
#pragma unroll
      for (int c = 0; c < 5; ++c)
        kreg[c] = *reinterpret_cast<const v8bf*>(kg + c * 512 + lane * 8);
    }

    // ---- QK(it): S^T[key][q] ----
    v4f sacc[4][2];
#pragma unroll
    for (int qt = 0; qt < 4; ++qt) {
      sacc[qt][0] = (v4f){0.f, 0.f, 0.f, 0.f};
      sacc[qt][1] = (v4f){0.f, 0.f, 0.f, 0.f};
    }
    __builtin_amdgcn_s_setprio(1);
#pragma unroll
    for (int s = 0; s < 3; ++s) {
      v8bf ak0 = *reinterpret_cast<const v8bf*>(
          &ksw[l15 * LQ + s * 32 + quad * 8]);
      v8bf ak1 = *reinterpret_cast<const v8bf*>(
          &ksw[(16 + l15) * LQ + s * 32 + quad * 8]);
#pragma unroll
      for (int qt = 0; qt < 4; ++qt) {
        sacc[qt][0] = __builtin_amdgcn_mfma_f32_16x16x32_bf16(
            ak0, qf[qt][s], sacc[qt][0], 0, 0, 0);
        sacc[qt][1] = __builtin_amdgcn_mfma_f32_16x16x32_bf16(
            ak1, qf[qt][s], sacc[qt][1], 0, 0, 0);
      }
    }

    // V(it) loads: contiguous tile (w*16+it), 5 linear b128 per lane
    v8bf vreg[5];
    {
      const __bf16* vg = vgb + (size_t)(w * 16 + it) * (KT * DHh);
#pragma unroll
      for (int c = 0; c < 5; ++c)
        vreg[c] = *reinterpret_cast<const v8bf*>(vg + c * 512 + lane * 8);
    }

    // ---- PV(it-1); exp2(it) fills its shadow ----
    if (it > 0) {
      v8bf bp[4];
#pragma unroll
      for (int qt = 0; qt < 4; ++qt)
        bp[qt] = *reinterpret_cast<const v8bf*>(
            &psw[(qt * 16 + l15) * LV + quad * 8]);
#pragma unroll
      for (int mt = 0; mt < 6; ++mt) {
        v8bf av = *reinterpret_cast<const v8bf*>(
            &vtw[(mt * 16 + l15) * LV + quad * 8]);
#pragma unroll
        for (int qt = 0; qt < 4; ++qt)
          Oacc[qt][mt] = __builtin_amdgcn_mfma_f32_16x16x32_bf16(
              av, bp[qt], Oacc[qt][mt], 0, 0, 0);
      }
    }
    __builtin_amdgcn_s_setprio(0);

    // ---- softmax(it): P = exp2(S) -> ps (raw v_exp_f32) ----
#pragma unroll
    for (int qt = 0; qt < 4; ++qt)
#pragma unroll
      for (int mt = 0; mt < 2; ++mt) {
        v4bf pk;
#pragma unroll
        for (int r = 0; r < 4; ++r)
          pk[r] = (__bf16)exp2_hw(sacc[qt][mt][r]);
        *reinterpret_cast<v4bf*>(
            &psw[(qt * 16 + l15) * LV + mt * 16 + quad * 4]) = pk;
      }

    // ---- commits ----
    if (pfK) {
#pragma unroll
      for (int c = 0; c < 5; ++c)
        *reinterpret_cast<v8bf*>(&ksw[klr[c]]) = kreg[c];
    }
#pragma unroll
    for (int c = 0; c < 5; ++c)
      *reinterpret_cast<v8bf*>(&vtw[vlo + c * 16 * LV]) = vreg[c];
  }

  // ---- pipeline epilogue: PV(NIT-1) ----
  {
    v8bf bp[4];
#pragma unroll
    for (int qt = 0; qt < 4; ++qt)
      bp[qt] = *reinterpret_cast<const v8bf*>(
          &psw[(qt * 16 + l15) * LV + quad * 8]);
    __builtin_amdgcn_s_setprio(1);
#pragma unroll
    for (int mt = 0; mt < 6; ++mt) {
      v8bf av = *reinterpret_cast<const v8bf*>(
          &vtw[(mt * 16 + l15) * LV + quad * 8]);
#pragma unroll
      for (int qt = 0; qt < 4; ++qt)
        Oacc[qt][mt] = __builtin_amdgcn_mfma_f32_16x16x32_bf16(
            av, bp[qt], Oacc[qt][mt], 0, 0, 0);
    }
    __builtin_amdgcn_s_setprio(0);
  }

  // ---- tree-merge the 4 per-wave partials ----
  __syncthreads();
  float* mrg = (float*)smem;
  if (w >= 2) {
    float* base = mrg + (w - 2) * (QT * LM);
#pragma unroll
    for (int qt = 0; qt < 4; ++qt)
#pragma unroll
      for (int mt = 0; mt < 6; ++mt)
        *reinterpret_cast<v4f*>(
            &base[(qt * 16 + l15) * LM + mt * 16 + quad * 4]) = Oacc[qt][mt];
  }
  __syncthreads();
  if (w < 2) {
    const float* base = mrg + w * (QT * LM);
#pragma unroll
    for (int qt = 0; qt < 4; ++qt)
#pragma unroll
      for (int mt = 0; mt < 6; ++mt)
        Oacc[qt][mt] += *reinterpret_cast<const v4f*>(
            &base[(qt * 16 + l15) * LM + mt * 16 + quad * 4]);
  }
  __syncthreads();
  if (w == 1) {
#pragma unroll
    for (int qt = 0; qt < 4; ++qt)
#pragma unroll
      for (int mt = 0; mt < 6; ++mt)
        *reinterpret_cast<v4f*>(
            &mrg[(qt * 16 + l15) * LM + mt * 16 + quad * 4]) = Oacc[qt][mt];
  }
  __syncthreads();
  if (w == 0) {
#pragma unroll
    for (int qt = 0; qt < 4; ++qt)
#pragma unroll
      for (int mt = 0; mt < 6; ++mt)
        Oacc[qt][mt] += *reinterpret_cast<const v4f*>(
            &mrg[(qt * 16 + l15) * LM + mt * 16 + quad * 4]);
#pragma unroll
    for (int qt = 0; qt < 4; ++qt) {
      float lsum = __shfl(Oacc[qt][5][0], l15);
      float inv = 1.f / lsum;
      __bf16* og =
          o + (size_t)(b * Ss + q0 + qt * 16 + l15) * Dd + h * DHh;
#pragma unroll
      for (int mt = 0; mt < 5; ++mt) {
        v4bf pk;
#pragma unroll
        for (int r = 0; r < 4; ++r) pk[r] = (__bf16)(Oacc[qt][mt][r] * inv);
        *reinterpret_cast<v4bf*>(&og[mt * 16 + quad * 4]) = pk;
      }
    }
  }
}

extern "C" void kernel_launch(void* const* d_in, const int* in_sizes, int n_in,
                              void* d_out, int out_size, void* d_ws,
                              size_t ws_size, hipStream_t stream) {
  const float* x   = (const float*)d_in[0];
  const float* ehs = (const float*)d_in[1];
  const float* Wq  = (const float*)d_in[2];
  const float* Wk  = (const float*)d_in[3];
  const float* Wv  = (const float*)d_in[4];
  const float* Wo  = (const float*)d_in[5];
  const float* bo  = (const float*)d_in[6];
  float* out = (float*)d_out;

  __bf16* qb  = (__bf16*)d_ws;                 // Q head-packed [2][8][2048][80]
  __bf16* kb  = qb + (size_t)Mm * Dd;          // K head-packed [2][8][2048][80]
  __bf16* vb  = kb + (size_t)Mm * Dd;          // V^T tiled [2][8][64][80][32]
  __bf16* ab  = vb + (size_t)Mm * Dd;          // attention output [tok][640]
  __bf16* Wtq = ab + (size_t)Mm * Dd;          // [640][640] transposed
  __bf16* Wtk = Wtq + (size_t)Dd * Dd;
  __bf16* Wtv = Wtk + (size_t)Dd * Dd;
  __bf16* Wto = Wtv + (size_t)Dd * Dd;

  wtrans_kernel<<<dim3(Dd / 32, Dd / 32, 4), 256, 0, stream>>>(
      Wq, Wk, Wv, Wo, Wtq, Wtk, Wtv, Wto);
  gemm_qkv_mfma<<<dim3(Dd / 128, Mm / 128, 3), 256, 0, stream>>>(
      x, ehs, Wtq, Wtk, Wtv, qb, kb, vb);
  attn_mfma_kernel<<<dim3(Bb * Hh, Ss / 64), 256, 0, stream>>>(qb, kb, vb, ab);
  gemm_out_mfma<<<dim3(Dd / 64, Mm / 128), 256, 0, stream>>>(ab, Wto, bo,
                                                             out);
}

// Round 12
// 146.547 us; speedup vs baseline: 1.1922x; 1.0086x over previous
//
#include <hip/hip_runtime.h>
#include <hip/hip_bf16.h>

typedef __bf16 v4bf __attribute__((ext_vector_type(4)));
typedef __bf16 v8bf __attribute__((ext_vector_type(8)));
typedef float  v4f  __attribute__((ext_vector_type(4)));

namespace {
constexpr int Bb  = 2;
constexpr int Ss  = 2048;
constexpr int Dd  = 640;
constexpr int Hh  = 8;
constexpr int DHh = 80;
constexpr int Mm  = Bb * Ss;          // 4096 rows
// scale * log2(e): softmax done in exp2 domain; folded into Q projection
constexpr float kQScale = 0.11180339887498949f * 1.4426950408889634f;

__device__ __forceinline__ float4 ld4(const float* p) {
  return *reinterpret_cast<const float4*>(p);
}

__device__ __forceinline__ v8bf pack8(float4 f0, float4 f1) {
  v8bf p;
  p[0]=(__bf16)f0.x; p[1]=(__bf16)f0.y; p[2]=(__bf16)f0.z; p[3]=(__bf16)f0.w;
  p[4]=(__bf16)f1.x; p[5]=(__bf16)f1.y; p[6]=(__bf16)f1.z; p[7]=(__bf16)f1.w;
  return p;
}

// raw v_exp_f32 (2^x): measured −5.7us vs libm exp2f (R9 A/B). Arg bounded.
__device__ __forceinline__ float exp2_hw(float x) {
  float r;
  asm("v_exp_f32 %0, %1" : "=v"(r) : "v"(x));
  return r;
}
}  // namespace

// ---------------------------------------------------------------------------
// Pre-kernel: W [k][n] fp32 -> Wt [n][k] bf16 (cast + transpose).
// ---------------------------------------------------------------------------
__global__ __launch_bounds__(256)
void wtrans_kernel(const float* __restrict__ Wq, const float* __restrict__ Wk,
                   const float* __restrict__ Wv, const float* __restrict__ Wo,
                   __bf16* __restrict__ Wtq, __bf16* __restrict__ Wtk,
                   __bf16* __restrict__ Wtv, __bf16* __restrict__ Wto) {
  const int z = blockIdx.z;
  const float* W = (z == 0) ? Wq : (z == 1) ? Wk : (z == 2) ? Wv : Wo;
  __bf16* Wt = (z == 0) ? Wtq : (z == 1) ? Wtk : (z == 2) ? Wtv : Wto;
  const int k0 = blockIdx.y * 32, n0 = blockIdx.x * 32;
  __shared__ float t[32][33];
  const int tid = threadIdx.x;
  {
    int kr = tid >> 3, c4 = (tid & 7) * 4;
    float4 f = ld4(W + (size_t)(k0 + kr) * Dd + n0 + c4);
    t[kr][c4 + 0] = f.x; t[kr][c4 + 1] = f.y;
    t[kr][c4 + 2] = f.z; t[kr][c4 + 3] = f.w;
  }
  __syncthreads();
  {
    int nr = tid >> 3, kc = (tid & 7) * 4;
    v4bf p;
#pragma unroll
    for (int u = 0; u < 4; ++u) p[u] = (__bf16)t[kc + u][nr];
    *reinterpret_cast<v4bf*>(&Wt[(size_t)(n0 + nr) * Dd + k0 + kc]) = p;
  }
}

// ---------------------------------------------------------------------------
// Double-buffered MFMA GEMM core (reg-staged, fp32 A). 128x128, BK=32.
// Used by the QKV projection.
// ---------------------------------------------------------------------------
__device__ __forceinline__ void gemm_core_db(const float* __restrict__ Af,
                                             const __bf16* __restrict__ Bt,
                                             __bf16* As, __bf16* Bs, int m0,
                                             int n0, int rh, int ch,
                                             v4f acc[4][4]) {
  constexpr int BUF = 128 * 40;  // elements per buffer
  constexpr int NKB = Dd / 32;   // 20 K-steps
  const int tid = threadIdx.x;
  const int lane = tid & 63;
  const int quad = lane >> 4, l15 = lane & 15;
  const int lr = tid >> 1;
  const int lk = (tid & 1) * 16;
  const __bf16* Bg = Bt + (size_t)(n0 + lr) * Dd + lk;

#pragma unroll
  for (int i = 0; i < 4; ++i)
#pragma unroll
    for (int j = 0; j < 4; ++j) acc[i][j] = (v4f){0.f, 0.f, 0.f, 0.f};

  v8bf a0, a1, b0, b1;
  {
    const float* ap = Af + (size_t)(m0 + lr) * Dd + lk;
    a0 = pack8(ld4(ap), ld4(ap + 4));
    a1 = pack8(ld4(ap + 8), ld4(ap + 12));
  }
  b0 = *reinterpret_cast<const v8bf*>(Bg);
  b1 = *reinterpret_cast<const v8bf*>(Bg + 8);
  *reinterpret_cast<v8bf*>(&As[lr * 40 + lk])     = a0;
  *reinterpret_cast<v8bf*>(&As[lr * 40 + lk + 8]) = a1;
  *reinterpret_cast<v8bf*>(&Bs[lr * 40 + lk])     = b0;
  *reinterpret_cast<v8bf*>(&Bs[lr * 40 + lk + 8]) = b1;

  for (int it = 0; it < NKB; ++it) {
    if (it + 1 < NKB) {
      const int kb = (it + 1) * 32;
      const float* ap = Af + (size_t)(m0 + lr) * Dd + kb + lk;
      a0 = pack8(ld4(ap), ld4(ap + 4));
      a1 = pack8(ld4(ap + 8), ld4(ap + 12));
      b0 = *reinterpret_cast<const v8bf*>(Bg + kb);
      b1 = *reinterpret_cast<const v8bf*>(Bg + kb + 8);
    }
    __syncthreads();
    const int cur = (it & 1) * BUF, nxt = BUF - cur;
    v8bf af[4], bv[4];
#pragma unroll
    for (int i = 0; i < 4; ++i)
      af[i] = *reinterpret_cast<const v8bf*>(
          &As[cur + (rh + i * 16 + l15) * 40 + quad * 8]);
#pragma unroll
    for (int j = 0; j < 4; ++j)
      bv[j] = *reinterpret_cast<const v8bf*>(
          &Bs[cur + (ch + j * 16 + l15) * 40 + quad * 8]);
#pragma unroll
    for (int i = 0; i < 4; ++i)
#pragma unroll
      for (int j = 0; j < 4; ++j)
        acc[i][j] = __builtin_amdgcn_mfma_f32_16x16x32_bf16(af[i], bv[j],
                                                            acc[i][j], 0, 0, 0);
    if (it + 1 < NKB) {
      *reinterpret_cast<v8bf*>(&As[nxt + lr * 40 + lk])     = a0;
      *reinterpret_cast<v8bf*>(&As[nxt + lr * 40 + lk + 8]) = a1;
      *reinterpret_cast<v8bf*>(&Bs[nxt + lr * 40 + lk])     = b0;
      *reinterpret_cast<v8bf*>(&Bs[nxt + lr * 40 + lk + 8]) = b1;
    }
  }
}

// QKV projections. z==0/1 -> Q/K HEAD-PACKED [b][h][tok][80] (Q pre-scaled);
// z==2 -> V^T TILED [b][h][tok/32][80][32].
__global__ __launch_bounds__(256)
void gemm_qkv_mfma(const float* __restrict__ x, const float* __restrict__ ehs,
                   const __bf16* __restrict__ Wtq,
                   const __bf16* __restrict__ Wtk,
                   const __bf16* __restrict__ Wtv, __bf16* __restrict__ qb,
                   __bf16* __restrict__ kbuf, __bf16* __restrict__ vb) {
  const int z = blockIdx.z;
  const float* A = (z == 0) ? x : ehs;
  const __bf16* Bt = (z == 0) ? Wtq : (z == 1) ? Wtk : Wtv;
  __bf16* C = (z == 0) ? qb : (z == 1) ? kbuf : vb;
  const float scale = (z == 0) ? kQScale : 1.0f;

  __shared__ __bf16 As[2 * 128 * 40];
  __shared__ __bf16 Bs[2 * 128 * 40];
  const int tid = threadIdx.x;
  const int w = tid >> 6, lane = tid & 63;
  const int quad = lane >> 4, l15 = lane & 15;
  const int m0 = blockIdx.y * 128, n0 = blockIdx.x * 128;
  const int rh = (w >> 1) * 64, ch = (w & 1) * 64;
  v4f acc[4][4];
  gemm_core_db(A, Bt, As, Bs, m0, n0, rh, ch, acc);

  if (z == 2) {
    // V^T tiled epilogue: vb[((b*Hh+h)*(Ss/32)+tb)*80 + d][t 0..31]
#pragma unroll
    for (int i = 0; i < 4; ++i)
#pragma unroll
      for (int j = 0; j < 4; ++j) {
        int m = m0 + rh + i * 16 + quad * 4;  // token (4 consecutive)
        int n = n0 + ch + j * 16 + l15;       // feature dim
        int hh = n / DHh, d = n % DHh;
        int bb = m >> 11, tok = m & 2047;
        int tb = tok >> 5, t = tok & 31;
        v4bf pk;
#pragma unroll
        for (int r = 0; r < 4; ++r) pk[r] = (__bf16)acc[i][j][r];
        *reinterpret_cast<v4bf*>(
            &C[((((size_t)bb * Hh + hh) * (Ss / 32) + tb) * DHh + d) * 32 +
               t]) = pk;
      }
  } else {
    // head-packed epilogue: C[((b*Hh+h)*Ss + tok)*80 + d]
#pragma unroll
    for (int i = 0; i < 4; ++i)
#pragma unroll
      for (int j = 0; j < 4; ++j) {
        int m = m0 + rh + i * 16 + quad * 4;
        int n = n0 + ch + j * 16 + l15;
        int hh = n / DHh, d = n % DHh;
        int bb = m >> 11, tok = m & 2047;
        __bf16* base = &C[(((size_t)bb * Hh + hh) * Ss + tok) * DHh + d];
#pragma unroll
        for (int r = 0; r < 4; ++r)
          base[(size_t)r * DHh] = (__bf16)(acc[i][j][r] * scale);
      }
  }
}

// ---------------------------------------------------------------------------
// Out-projection: tile 128M x 64N -> grid 320 blocks. 4 waves, each 64x32.
// ---------------------------------------------------------------------------
__global__ __launch_bounds__(256)
void gemm_out_mfma(const __bf16* __restrict__ A, const __bf16* __restrict__ Bt,
                   const float* __restrict__ bias, float* __restrict__ out) {
  constexpr int BUFA = 128 * 40, BUFB = 64 * 40;
  constexpr int NKB = Dd / 32;
  __shared__ __bf16 As[2 * BUFA];
  __shared__ __bf16 Bs[2 * BUFB];
  const int tid = threadIdx.x;
  const int w = tid >> 6, lane = tid & 63;
  const int quad = lane >> 4, l15 = lane & 15;
  const int m0 = blockIdx.y * 128, n0 = blockIdx.x * 64;
  const int rh = (w >> 1) * 64, ch = (w & 1) * 32;
  const int lrA = tid >> 1, lkA = (tid & 1) * 16;
  const int lrB = tid >> 2, lkB = (tid & 3) * 8;
  const __bf16* Ag = A + (size_t)(m0 + lrA) * Dd + lkA;
  const __bf16* Bg = Bt + (size_t)(n0 + lrB) * Dd + lkB;

  v4f acc[4][2];
#pragma unroll
  for (int i = 0; i < 4; ++i)
#pragma unroll
    for (int j = 0; j < 2; ++j) acc[i][j] = (v4f){0.f, 0.f, 0.f, 0.f};

  v8bf a0, a1, b0;
  a0 = *reinterpret_cast<const v8bf*>(Ag);
  a1 = *reinterpret_cast<const v8bf*>(Ag + 8);
  b0 = *reinterpret_cast<const v8bf*>(Bg);
  *reinterpret_cast<v8bf*>(&As[lrA * 40 + lkA])     = a0;
  *reinterpret_cast<v8bf*>(&As[lrA * 40 + lkA + 8]) = a1;
  *reinterpret_cast<v8bf*>(&Bs[lrB * 40 + lkB])     = b0;

  for (int it = 0; it < NKB; ++it) {
    if (it + 1 < NKB) {
      const int kb = (it + 1) * 32;
      a0 = *reinterpret_cast<const v8bf*>(Ag + kb);
      a1 = *reinterpret_cast<const v8bf*>(Ag + kb + 8);
      b0 = *reinterpret_cast<const v8bf*>(Bg + kb);
    }
    __syncthreads();
    const int curA = (it & 1) * BUFA, nxtA = BUFA - curA;
    const int curB = (it & 1) * BUFB, nxtB = BUFB - curB;
    v8bf af[4], bv[2];
#pragma unroll
    for (int i = 0; i < 4; ++i)
      af[i] = *reinterpret_cast<const v8bf*>(
          &As[curA + (rh + i * 16 + l15) * 40 + quad * 8]);
#pragma unroll
    for (int j = 0; j < 2; ++j)
      bv[j] = *reinterpret_cast<const v8bf*>(
          &Bs[curB + (ch + j * 16 + l15) * 40 + quad * 8]);
#pragma unroll
    for (int i = 0; i < 4; ++i)
#pragma unroll
      for (int j = 0; j < 2; ++j)
        acc[i][j] = __builtin_amdgcn_mfma_f32_16x16x32_bf16(af[i], bv[j],
                                                            acc[i][j], 0, 0, 0);
    if (it + 1 < NKB) {
      *reinterpret_cast<v8bf*>(&As[nxtA + lrA * 40 + lkA])     = a0;
      *reinterpret_cast<v8bf*>(&As[nxtA + lrA * 40 + lkA + 8]) = a1;
      *reinterpret_cast<v8bf*>(&Bs[nxtB + lrB * 40 + lkB])     = b0;
    }
  }

#pragma unroll
  for (int i = 0; i < 4; ++i)
#pragma unroll
    for (int j = 0; j < 2; ++j) {
      int m = m0 + rh + i * 16 + quad * 4;
      int n = n0 + ch + j * 16 + l15;
      float bn = bias[n];
#pragma unroll
      for (int r = 0; r < 4; ++r)
        out[(size_t)(m + r) * Dd + n] = acc[i][j][r] + bn;
    }
}

// ---------------------------------------------------------------------------
// Barrier-free key-split MFMA flash attention (R12): K and V consumed
// DIRECTLY from global as MFMA fragments — in key-split there is no
// cross-wave sharing, so LDS-staging them was pure overhead (the measured
// per-pipe budget: LDS ~65% busy vs MFMA 31%; the guide's documented trap
// "LDS-staging data that cache-fits"). LDS now holds ONLY the P tile
// (ps->bp layout redistribution). l-sum ones-row becomes a constant
// register fragment (l15==0 ? ones : 0). LDS ops/iter/wave 29 -> 12,
// footprint 77.8 -> 50 KB (merge buffer now dominates).
// Pipeline order preserved: QK(it) -> PV(it-1){bp reads} -> softmax(it)
// {ps writes} — per-wave in-order LDS guarantees read-before-overwrite.
// ---------------------------------------------------------------------------
__global__ __launch_bounds__(256, 2)
void attn_mfma_kernel(const __bf16* __restrict__ q,
                      const __bf16* __restrict__ k,
                      const __bf16* __restrict__ vtg, __bf16* __restrict__ o) {
  constexpr int QT = 64;            // q rows per block (all waves)
  constexpr int KT = 32;            // keys per iteration per wave
  constexpr int KW = Ss / 4;        // 512 keys per wave
  constexpr int NIT = KW / KT;      // 16 iterations
  constexpr int LV = 40;            // P row stride (32 keys + 8 pad)
  constexpr int PS = QT * LV;       // 2560 bf16 per wave (5120 B)
  constexpr int LM = 100;           // merge row stride (f32)

  // merge buffer dominates LDS: 2*QT*LM f32 = 51200 B; ps aliases low part
  __shared__ __align__(16) float smem_f[2 * QT * LM];

  const int bh = blockIdx.x;        // XCD = linear%8 = bh%8 -> L2 locality
  const int b = bh >> 3, h = bh & 7;
  const int q0 = blockIdx.y * QT;
  const int tid = threadIdx.x;
  const int w = tid >> 6;
  const int lane = tid & 63;
  const int quad = lane >> 4;
  const int l15 = lane & 15;

  __bf16* psw = reinterpret_cast<__bf16*>(smem_f) + w * PS;

  const __bf16* qg  = q + ((size_t)(b * Hh + h) * Ss + q0) * DHh;
  const __bf16* kgb = k + (size_t)(b * Hh + h) * Ss * DHh;   // [tok][80]
  const __bf16* vgb = vtg + (size_t)(b * Hh + h) * Ss * DHh; // tiled [64][80][32]

  // ---- Q B-fragments from global (n=q=l15, k=dim; dims 80..95 = 0) ----
  v8bf qf[4][3];
#pragma unroll
  for (int qt = 0; qt < 4; ++qt)
#pragma unroll
    for (int s = 0; s < 3; ++s) {
      if (s == 2 && quad >= 2) {
        qf[qt][s] = (v8bf){};
      } else {
        qf[qt][s] = *reinterpret_cast<const v8bf*>(
            qg + (size_t)(qt * 16 + l15) * DHh + s * 32 + quad * 8);
      }
    }

  // ---- l-sum constant A-fragment: row(l15)==0 -> ones, else zero.
  //      mfma(av5, P) accumulates sum_k P[k][q] into Oacc[qt][5] row 0. ----
  v8bf av5 = {};
  if (l15 == 0) {
#pragma unroll
    for (int e = 0; e < 8; ++e) av5[e] = (__bf16)1.f;
  }

  // ---- K A-fragments direct from global: row=key (h16*16+l15), k=dim ----
  v8bf kc[3][2];
#pragma unroll
  for (int s = 0; s < 3; ++s)
#pragma unroll
    for (int h16 = 0; h16 < 2; ++h16) {
      v8bf t = {};
      if (!(s == 2 && quad >= 2))
        t = *reinterpret_cast<const v8bf*>(
            kgb + (size_t)(w * KW + h16 * 16 + l15) * DHh + s * 32 + quad * 8);
      kc[s][h16] = t;
    }

  v4f Oacc[4][6];
#pragma unroll
  for (int qt = 0; qt < 4; ++qt)
#pragma unroll
    for (int mt = 0; mt < 6; ++mt) Oacc[qt][mt] = (v4f){0.f, 0.f, 0.f, 0.f};

  v8bf vf[5];
  // ---- main loop: per-wave, no barriers; 1-deep software pipeline ----
  for (int it = 0; it < NIT; ++it) {
    // V A-fragments for PV(it-1): tiled tile (w*16 + it-1), fully coalesced
    if (it > 0) {
      const __bf16* vg = vgb + (size_t)(w * 16 + (it - 1)) * (KT * DHh);
#pragma unroll
      for (int mt = 0; mt < 5; ++mt)
        vf[mt] = *reinterpret_cast<const v8bf*>(vg + (mt * 16 + l15) * 32 +
                                                quad * 8);
    }

    // ---- QK(it): S^T[key][q] from kc fragments ----
    v4f sacc[4][2];
#pragma unroll
    for (int qt = 0; qt < 4; ++qt) {
      sacc[qt][0] = (v4f){0.f, 0.f, 0.f, 0.f};
      sacc[qt][1] = (v4f){0.f, 0.f, 0.f, 0.f};
    }
    __builtin_amdgcn_s_setprio(1);
#pragma unroll
    for (int s = 0; s < 3; ++s) {
#pragma unroll
      for (int qt = 0; qt < 4; ++qt) {
        sacc[qt][0] = __builtin_amdgcn_mfma_f32_16x16x32_bf16(
            kc[s][0], qf[qt][s], sacc[qt][0], 0, 0, 0);
        sacc[qt][1] = __builtin_amdgcn_mfma_f32_16x16x32_bf16(
            kc[s][1], qf[qt][s], sacc[qt][1], 0, 0, 0);
      }
    }

    // ---- prefetch K(it+1) fragments (consumed next iter) ----
    v8bf kn[3][2];
    if (it + 1 < NIT) {
#pragma unroll
      for (int s = 0; s < 3; ++s)
#pragma unroll
        for (int h16 = 0; h16 < 2; ++h16) {
          v8bf t = {};
          if (!(s == 2 && quad >= 2))
            t = *reinterpret_cast<const v8bf*>(
                kgb + (size_t)(w * KW + (it + 1) * KT + h16 * 16 + l15) * DHh +
                s * 32 + quad * 8);
          kn[s][h16] = t;
        }
    }

    // ---- PV(it-1): bp read BEFORE softmax(it) overwrites ps ----
    if (it > 0) {
      v8bf bp[4];
#pragma unroll
      for (int qt = 0; qt < 4; ++qt)
        bp[qt] = *reinterpret_cast<const v8bf*>(
            &psw[(qt * 16 + l15) * LV + quad * 8]);
#pragma unroll
      for (int mt = 0; mt < 5; ++mt)
#pragma unroll
        for (int qt = 0; qt < 4; ++qt)
          Oacc[qt][mt] = __builtin_amdgcn_mfma_f32_16x16x32_bf16(
              vf[mt], bp[qt], Oacc[qt][mt], 0, 0, 0);
#pragma unroll
      for (int qt = 0; qt < 4; ++qt)
        Oacc[qt][5] = __builtin_amdgcn_mfma_f32_16x16x32_bf16(
            av5, bp[qt], Oacc[qt][5], 0, 0, 0);
    }
    __builtin_amdgcn_s_setprio(0);

    // ---- softmax(it): P = exp2(S) -> ps (raw v_exp_f32) ----
#pragma unroll
    for (int qt = 0; qt < 4; ++qt)
#pragma unroll
      for (int mt = 0; mt < 2; ++mt) {
        v4bf pk;
#pragma unroll
        for (int r = 0; r < 4; ++r)
          pk[r] = (__bf16)exp2_hw(sacc[qt][mt][r]);
        *reinterpret_cast<v4bf*>(
            &psw[(qt * 16 + l15) * LV + mt * 16 + quad * 4]) = pk;
      }

    if (it + 1 < NIT) {
#pragma unroll
      for (int s = 0; s < 3; ++s)
#pragma unroll
        for (int h16 = 0; h16 < 2; ++h16) kc[s][h16] = kn[s][h16];
    }
  }

  // ---- pipeline epilogue: PV(NIT-1) ----
  {
    const __bf16* vg = vgb + (size_t)(w * 16 + (NIT - 1)) * (KT * DHh);
#pragma unroll
    for (int mt = 0; mt < 5; ++mt)
      vf[mt] = *reinterpret_cast<const v8bf*>(vg + (mt * 16 + l15) * 32 +
                                              quad * 8);
    v8bf bp[4];
#pragma unroll
    for (int qt = 0; qt < 4; ++qt)
      bp[qt] = *reinterpret_cast<const v8bf*>(
          &psw[(qt * 16 + l15) * LV + quad * 8]);
    __builtin_amdgcn_s_setprio(1);
#pragma unroll
    for (int mt = 0; mt < 5; ++mt)
#pragma unroll
      for (int qt = 0; qt < 4; ++qt)
        Oacc[qt][mt] = __builtin_amdgcn_mfma_f32_16x16x32_bf16(
            vf[mt], bp[qt], Oacc[qt][mt], 0, 0, 0);
#pragma unroll
    for (int qt = 0; qt < 4; ++qt)
      Oacc[qt][5] = __builtin_amdgcn_mfma_f32_16x16x32_bf16(
          av5, bp[qt], Oacc[qt][5], 0, 0, 0);
    __builtin_amdgcn_s_setprio(0);
  }

  // ---- tree-merge the 4 per-wave partials (plain f32 sums) ----
  __syncthreads();
  float* mrg = smem_f;
  if (w >= 2) {
    float* base = mrg + (w - 2) * (QT * LM);
#pragma unroll
    for (int qt = 0; qt < 4; ++qt)
#pragma unroll
      for (int mt = 0; mt < 6; ++mt)
        *reinterpret_cast<v4f*>(
            &base[(qt * 16 + l15) * LM + mt * 16 + quad * 4]) = Oacc[qt][mt];
  }
  __syncthreads();
  if (w < 2) {
    const float* base = mrg + w * (QT * LM);
#pragma unroll
    for (int qt = 0; qt < 4; ++qt)
#pragma unroll
      for (int mt = 0; mt < 6; ++mt)
        Oacc[qt][mt] += *reinterpret_cast<const v4f*>(
            &base[(qt * 16 + l15) * LM + mt * 16 + quad * 4]);
  }
  __syncthreads();
  if (w == 1) {
#pragma unroll
    for (int qt = 0; qt < 4; ++qt)
#pragma unroll
      for (int mt = 0; mt < 6; ++mt)
        *reinterpret_cast<v4f*>(
            &mrg[(qt * 16 + l15) * LM + mt * 16 + quad * 4]) = Oacc[qt][mt];
  }
  __syncthreads();
  if (w == 0) {
#pragma unroll
    for (int qt = 0; qt < 4; ++qt)
#pragma unroll
      for (int mt = 0; mt < 6; ++mt)
        Oacc[qt][mt] += *reinterpret_cast<const v4f*>(
            &mrg[(qt * 16 + l15) * LM + mt * 16 + quad * 4]);
#pragma unroll
    for (int qt = 0; qt < 4; ++qt) {
      float lsum = __shfl(Oacc[qt][5][0], l15);
      float inv = 1.f / lsum;
      __bf16* og =
          o + (size_t)(b * Ss + q0 + qt * 16 + l15) * Dd + h * DHh;
#pragma unroll
      for (int mt = 0; mt < 5; ++mt) {
        v4bf pk;
#pragma unroll
        for (int r = 0; r < 4; ++r) pk[r] = (__bf16)(Oacc[qt][mt][r] * inv);
        *reinterpret_cast<v4bf*>(&og[mt * 16 + quad * 4]) = pk;
      }
    }
  }
}

extern "C" void kernel_launch(void* const* d_in, const int* in_sizes, int n_in,
                              void* d_out, int out_size, void* d_ws,
                              size_t ws_size, hipStream_t stream) {
  const float* x   = (const float*)d_in[0];
  const float* ehs = (const float*)d_in[1];
  const float* Wq  = (const float*)d_in[2];
  const float* Wk  = (const float*)d_in[3];
  const float* Wv  = (const float*)d_in[4];
  const float* Wo  = (const float*)d_in[5];
  const float* bo  = (const float*)d_in[6];
  float* out = (float*)d_out;

  __bf16* qb  = (__bf16*)d_ws;                 // Q head-packed [2][8][2048][80]
  __bf16* kb  = qb + (size_t)Mm * Dd;          // K head-packed [2][8][2048][80]
  __bf16* vb  = kb + (size_t)Mm * Dd;          // V^T tiled [2][8][64][80][32]
  __bf16* ab  = vb + (size_t)Mm * Dd;          // attention output [tok][640]
  __bf16* Wtq = ab + (size_t)Mm * Dd;          // [640][640] transposed
  __bf16* Wtk = Wtq + (size_t)Dd * Dd;
  __bf16* Wtv = Wtk + (size_t)Dd * Dd;
  __bf16* Wto = Wtv + (size_t)Dd * Dd;

  wtrans_kernel<<<dim3(Dd / 32, Dd / 32, 4), 256, 0, stream>>>(
      Wq, Wk, Wv, Wo, Wtq, Wtk, Wtv, Wto);
  gemm_qkv_mfma<<<dim3(Dd / 128, Mm / 128, 3), 256, 0, stream>>>(
      x, ehs, Wtq, Wtk, Wtv, qb, kb, vb);
  attn_mfma_kernel<<<dim3(Bb * Hh, Ss / 64), 256, 0, stream>>>(qb, kb, vb, ab);
  gemm_out_mfma<<<dim3(Dd / 64, Mm / 128), 256, 0, stream>>>(ab, Wto, bo,
                                                             out);
}